// Round 4
// baseline (499.146 us; speedup 1.0000x reference)
//
#include <hip/hip_runtime.h>
#include <hip/hip_fp16.h>
#include <math.h>

#define D1 128
#define NEG 0.2f
#define NODE_SHIFT 9
#define BIN_NODES 512
#define MAXBIN 256

typedef _Float16 v8h __attribute__((ext_vector_type(8)));
typedef float v4f __attribute__((ext_vector_type(4)));

__device__ __forceinline__ float elu_f(float v){ return v > 0.f ? v : __expf(v) - 1.f; }

__device__ __forceinline__ unsigned f2h2(float a, float b){           // a->low, b->high
    return ((unsigned)__half_as_ushort(__float2half_rn(b)) << 16) |
           (unsigned)__half_as_ushort(__float2half_rn(a));
}

// ---------------- binned CSR build ----------------
// staged entry: (dstLow << 17) | src   (src < 2^17, dstLow < 2^9)

__global__ __launch_bounds__(256) void kb_hist(const int* __restrict__ ei,
                                               int* __restrict__ binCnt,
                                               int n_edges, int etot, int nbin){
    __shared__ int h[MAXBIN];
    for (int i = threadIdx.x; i < nbin; i += 256) h[i] = 0;
    __syncthreads();
    int stride = gridDim.x * 256;
    for (int e = blockIdx.x * 256 + threadIdx.x; e < etot; e += stride){
        int dst = (e < n_edges) ? ei[n_edges + e] : (e - n_edges);
        atomicAdd(&h[dst >> NODE_SHIFT], 1);
    }
    __syncthreads();
    for (int i = threadIdx.x; i < nbin; i += 256)
        if (h[i]) atomicAdd(&binCnt[i], h[i]);
}

__global__ void kb_scan(const int* __restrict__ binCnt, int* __restrict__ binStart,
                        int* __restrict__ binCursor, int nbin,
                        int* __restrict__ rowptr, int n_nodes, int etot){
    if (threadIdx.x == 0){
        int run = 0;
        for (int b = 0; b < nbin; b++){
            binStart[b] = run; binCursor[b] = run; run += binCnt[b];
        }
        binStart[nbin] = run;
        rowptr[n_nodes] = etot;
    }
}

__global__ __launch_bounds__(256) void kb_scatter(const int* __restrict__ ei,
                                                  int* __restrict__ binCursor,
                                                  unsigned* __restrict__ staged,
                                                  int n_edges, int etot, int nbin){
    __shared__ int cnt[MAXBIN];
    __shared__ int base[MAXBIN];
    int e0 = blockIdx.x * 4096;
    for (int i = threadIdx.x; i < nbin; i += 256) cnt[i] = 0;
    __syncthreads();
    #pragma unroll 4
    for (int r = 0; r < 16; r++){
        int e = e0 + r * 256 + threadIdx.x;
        if (e < etot){
            int dst = (e < n_edges) ? ei[n_edges + e] : (e - n_edges);
            atomicAdd(&cnt[dst >> NODE_SHIFT], 1);
        }
    }
    __syncthreads();
    for (int i = threadIdx.x; i < nbin; i += 256){
        base[i] = cnt[i] ? atomicAdd(&binCursor[i], cnt[i]) : 0;
        cnt[i] = 0;
    }
    __syncthreads();
    #pragma unroll 4
    for (int r = 0; r < 16; r++){
        int e = e0 + r * 256 + threadIdx.x;
        if (e < etot){
            int src, dst;
            if (e < n_edges){ src = ei[e]; dst = ei[n_edges + e]; }
            else            { src = dst = e - n_edges; }
            int b = dst >> NODE_SHIFT;
            int p = base[b] + atomicAdd(&cnt[b], 1);
            staged[p] = ((unsigned)(dst & (BIN_NODES - 1)) << 17) | (unsigned)src;
        }
    }
}

__global__ __launch_bounds__(512) void kb_final(const unsigned* __restrict__ staged,
                                                const int* __restrict__ binStart,
                                                int* __restrict__ rowptr,
                                                int* __restrict__ eidx, int n_nodes){
    __shared__ int deg[BIN_NODES];
    __shared__ int cur[BIN_NODES];
    int b = blockIdx.x;
    int nbase = b << NODE_SHIFT;
    int s0 = binStart[b], s1 = binStart[b + 1];
    deg[threadIdx.x] = 0;
    __syncthreads();
    for (int i = s0 + threadIdx.x; i < s1; i += 512)
        atomicAdd(&deg[staged[i] >> 17], 1);
    __syncthreads();
    int v = deg[threadIdx.x];
    cur[threadIdx.x] = v;
    __syncthreads();
    for (int off = 1; off < BIN_NODES; off <<= 1){
        int t = (threadIdx.x >= off) ? cur[threadIdx.x - off] : 0;
        __syncthreads();
        cur[threadIdx.x] += t;
        __syncthreads();
    }
    int excl = cur[threadIdx.x] - v;           // exclusive prefix within bin
    int node = nbase + threadIdx.x;
    if (node < n_nodes) rowptr[node] = s0 + excl;
    cur[threadIdx.x] = s0 + excl;              // becomes cursor
    __syncthreads();
    for (int i = s0 + threadIdx.x; i < s1; i += 512){
        unsigned pr = staged[i];
        int p = atomicAdd(&cur[pr >> 17], 1);
        eidx[p] = (int)(pr & 0x1FFFFu);
    }
}

// ---------------- weight prep: f16 W, k-packed B' layout ----------------
// B[k][j] = W[j][k].  B'[kb][j][kk], kb=k>>3, kk=k&7 (f16 bits in ushort).

__global__ void k_prepw(const float* __restrict__ W1, const float* __restrict__ W2,
                        const float* __restrict__ W3, unsigned short* __restrict__ Bp){
    int t = blockIdx.x * 256 + threadIdx.x;          // 0..49151
    if (t >= 49152) return;
    int w = t >> 14;
    int r = t & 16383;
    int k = r >> 7, j = r & 127;
    const float* W = (w == 0) ? W1 : (w == 1) ? W2 : W3;
    float val = W[j * 128 + k];
    int idx = (k >> 3) * 1024 + j * 8 + (k & 7);
    Bp[w * 16384 + idx] = __half_as_ushort(__float2half_rn(val));
}

// ---------------- f16 MFMA GEMM + fused attention coefficients ----------------
// H = X @ W.T, all operands fp16, fp32 accumulate. A fragments fully hoisted
// (8 x v8h = 32 VGPR), B staged once in 32 KB LDS, one barrier, 64-MFMA stream.
// mfma_f32_16x16x32_f16: A[m=lane&15][k=quad*8+j]; C/D[row=quad*4+reg][col=lane&15].

template<int FP32SRC>
__global__ __launch_bounds__(256, 4) void k_mgemm(
        const float* __restrict__ Xf, const unsigned short* __restrict__ Xh,
        const unsigned short* __restrict__ Bp,
        const float* __restrict__ aw_s, const float* __restrict__ aw_d,
        unsigned short* __restrict__ Hh,
        float* __restrict__ asrc, float* __restrict__ adst, int n_rows){
    __shared__ unsigned short Bs[16384];         // 32 KB: whole B panel, f16
    int lane = threadIdx.x & 63;
    int wv   = threadIdx.x >> 6;
    int li = lane & 15, quad = lane >> 4;
    int r0 = blockIdx.x * 128 + wv * 32;

    int row0 = r0 + li;
    int row1 = r0 + 16 + li;
    int rc0 = row0 < n_rows ? row0 : 0;
    int rc1 = row1 < n_rows ? row1 : 0;

    // hoist all A fragments (independent of LDS staging)
    v8h a0[4], a1[4];
    #pragma unroll
    for (int ks = 0; ks < 4; ks++){
        int koff = ks * 32 + quad * 8;
        if (FP32SRC){
            float f0[8], f1[8];
            *(float4*)&f0[0] = *(const float4*)(Xf + (size_t)rc0 * 128 + koff);
            *(float4*)&f0[4] = *(const float4*)(Xf + (size_t)rc0 * 128 + koff + 4);
            *(float4*)&f1[0] = *(const float4*)(Xf + (size_t)rc1 * 128 + koff);
            *(float4*)&f1[4] = *(const float4*)(Xf + (size_t)rc1 * 128 + koff + 4);
            #pragma unroll
            for (int i = 0; i < 8; i++){
                a0[ks][i] = (_Float16)f0[i];
                a1[ks][i] = (_Float16)f1[i];
            }
        } else {
            a0[ks] = *(const v8h*)(Xh + (size_t)rc0 * 128 + koff);
            a1[ks] = *(const v8h*)(Xh + (size_t)rc1 * 128 + koff);
        }
    }

    // stage whole B panel: 2048 float4, 8 per thread
    #pragma unroll
    for (int i = 0; i < 8; i++){
        int idx = threadIdx.x + i * 256;
        ((float4*)Bs)[idx] = ((const float4*)Bp)[idx];
    }
    __syncthreads();

    v4f acc[2][8];
    #pragma unroll
    for (int m = 0; m < 2; m++)
        #pragma unroll
        for (int t = 0; t < 8; t++)
            acc[m][t] = (v4f){0.f, 0.f, 0.f, 0.f};

    #pragma unroll
    for (int ks = 0; ks < 4; ks++){
        #pragma unroll
        for (int t = 0; t < 8; t++){
            int bo = (ks * 4 + quad) * 1024 + (t * 16 + li) * 8;
            v8h b = *(const v8h*)(Bs + bo);
            acc[0][t] = __builtin_amdgcn_mfma_f32_16x16x32_f16(a0[ks], b, acc[0][t], 0, 0, 0);
            acc[1][t] = __builtin_amdgcn_mfma_f32_16x16x32_f16(a1[ks], b, acc[1][t], 0, 0, 0);
        }
    }

    // epilogue 1: fp16 mirror
    #pragma unroll
    for (int m = 0; m < 2; m++){
        #pragma unroll
        for (int t = 0; t < 8; t++){
            #pragma unroll
            for (int r = 0; r < 4; r++){
                float v  = acc[m][t][r];
                float vo = __shfl_xor(v, 1);
                if (!(li & 1)){
                    int row = r0 + m * 16 + quad * 4 + r;
                    if (row < n_rows)
                        *(unsigned*)(Hh + (size_t)row * 128 + t * 16 + li) = f2h2(v, vo);
                }
            }
        }
    }

    // epilogue 2: fused attention coefficients (fp32)
    float as8[8], ad8[8];
    #pragma unroll
    for (int t = 0; t < 8; t++){
        as8[t] = aw_s[t * 16 + li];
        ad8[t] = aw_d[t * 16 + li];
    }
    #pragma unroll
    for (int m = 0; m < 2; m++){
        #pragma unroll
        for (int r = 0; r < 4; r++){
            float sp[4], dp[4];
            #pragma unroll
            for (int h = 0; h < 4; h++){
                sp[h] = acc[m][2*h][r] * as8[2*h] + acc[m][2*h+1][r] * as8[2*h+1];
                dp[h] = acc[m][2*h][r] * ad8[2*h] + acc[m][2*h+1][r] * ad8[2*h+1];
            }
            #pragma unroll
            for (int off = 1; off < 16; off <<= 1){
                #pragma unroll
                for (int h = 0; h < 4; h++){
                    sp[h] += __shfl_xor(sp[h], off);
                    dp[h] += __shfl_xor(dp[h], off);
                }
            }
            if (li == 0){
                int row = r0 + m * 16 + quad * 4 + r;
                if (row < n_rows){
                    ((float4*)asrc)[row] = make_float4(sp[0], sp[1], sp[2], sp[3]);
                    ((float4*)adst)[row] = make_float4(dp[0], dp[1], dp[2], dp[3]);
                }
            }
        }
    }
}

// ---------------- fused softmax + aggregation, one wave per node ----------------
// x4-gather layout: lane l = 16g+m; slot t covers edges 4t..4t+3 (group g owns
// edge 4t+g); lane-chunk m owns feature pairs 4m..4m+3 (head m>>2). One dwordx4
// load fetches 4 H-rows. Only nt = ceil(rem/4) slots issue (wave-uniform guards).
// Inner accumulate uses explicit v_fma_mix_f32 (packed f16 src0, f32 acc) --
// guarantees 8 VALU/slot instead of 8 cvt + 8 fma. MEAN=1 additionally fuses
// the linear readout + graph mean-pool (slotted atomics, 64 slots/graph).

__device__ __forceinline__ void cons4(uint4 hv, float w, float* acc){
    unsigned u[4] = {hv.x, hv.y, hv.z, hv.w};
    #pragma unroll
    for (int q = 0; q < 4; q++){
        asm("v_fma_mix_f32 %0, %1, %2, %0 op_sel:[0,0,0] op_sel_hi:[1,0,0]"
            : "+v"(acc[2*q])     : "v"(u[q]), "v"(w));
        asm("v_fma_mix_f32 %0, %1, %2, %0 op_sel:[1,0,0] op_sel_hi:[1,0,0]"
            : "+v"(acc[2*q+1])   : "v"(u[q]), "v"(w));
    }
}

template<int MEAN>
__global__ __launch_bounds__(256, 8) void k_aggr(
        const unsigned* __restrict__ Hh,
        const float* __restrict__ asrc, const float* __restrict__ adst,
        const int* __restrict__ rowptr, const int* __restrict__ eidx,
        const float* __restrict__ bias,
        unsigned short* __restrict__ O,
        const int* __restrict__ batch, const float* __restrict__ lw,
        const float* __restrict__ lb,
        float* __restrict__ pool2, float* __restrict__ cnt2, int n_nodes){
    int lane = threadIdx.x & 63;
    int wid  = threadIdx.x >> 6;
    int n = __builtin_amdgcn_readfirstlane(blockIdx.x * 4 + wid);  // wave-uniform node
    if (n >= n_nodes) return;
    int row0 = rowptr[n];
    int deg  = rowptr[n + 1] - row0;
    const int* ep = eidx + row0;
    int l  = lane;
    int eh = l & 3;                        // weight-phase head
    int ej = l >> 2;                       // weight-phase edge slot (0..15)
    int m  = l & 15;                       // 16B chunk within row
    int wb = l & 60;                       // bpermute base: addr_t = ((t&3)<<6) + wb
    int hb = l & 12;                       // den bpermute addr (head m>>2)
    float4 ad = ((const float4*)adst)[n];
    float adw = eh == 0 ? ad.x : eh == 1 ? ad.y : eh == 2 ? ad.z : ad.w;

    const uint4* H4 = (const uint4*)Hh;
    float acc[8];                          // features 8m..8m+7, edges == g (mod 4)
    #pragma unroll
    for (int q = 0; q < 8; q++) acc[q] = 0.f;
    float denp = 0.f;

    for (int i = 0; i < deg; i += 32){
        int rem = deg - i; if (rem > 32) rem = 32;
        int last = i + rem - 1;

        int j0 = i + ej;
        int sv0 = ep[j0 < last ? j0 : last];
        float t0 = asrc[(size_t)(unsigned)sv0 * 4u + (unsigned)eh] + adw;
        float w0f = __expf(fmaxf(t0, NEG * t0));
        float w0 = (ej < rem) ? w0f : 0.f;
        denp += w0;
        int w0i = __float_as_int(w0);

        int sv1 = sv0;
        int w1i = 0;
        if (rem > 16){
            int j1 = i + 16 + ej;
            sv1 = ep[j1 < last ? j1 : last];
            float t1 = asrc[(size_t)(unsigned)sv1 * 4u + (unsigned)eh] + adw;
            float w1f = __expf(fmaxf(t1, NEG * t1));
            float w1 = (16 + ej < rem) ? w1f : 0.f;
            denp += w1;
            w1i = __float_as_int(w1);
        }

        uint4 hv0, hv1, hv2, hv3, hv4, hv5, hv6, hv7;
#define GLOAD(t, svx) \
        if ((t) * 4 < rem){ \
            int s_ = __builtin_amdgcn_ds_bpermute((((t) & 3) << 6) + wb, svx); \
            hv##t = H4[(unsigned)s_ * 16u + (unsigned)m]; \
        }
#define GCONS(t, wxi) \
        if ((t) * 4 < rem){ \
            float wt_ = __int_as_float(__builtin_amdgcn_ds_bpermute((((t) & 3) << 6) + wb, wxi)); \
            cons4(hv##t, wt_, acc); \
        }
        GLOAD(0, sv0) GLOAD(1, sv0) GLOAD(2, sv0) GLOAD(3, sv0)
        GLOAD(4, sv1) GLOAD(5, sv1) GLOAD(6, sv1) GLOAD(7, sv1)
        GCONS(0, w0i) GCONS(1, w0i) GCONS(2, w0i) GCONS(3, w0i)
        GCONS(4, w1i) GCONS(5, w1i) GCONS(6, w1i) GCONS(7, w1i)
#undef GLOAD
#undef GCONS
    }

    // reduce over edge groups g (lane bits 4,5)
    #pragma unroll
    for (int q = 0; q < 8; q++){
        acc[q] += __shfl_xor(acc[q], 16);
        acc[q] += __shfl_xor(acc[q], 32);
    }
    // denominator: sum over edge slots (bits 2..5), then pick head m>>2
    denp += __shfl_xor(denp, 4);
    denp += __shfl_xor(denp, 8);
    denp += __shfl_xor(denp, 16);
    denp += __shfl_xor(denp, 32);
    float den = __int_as_float(__builtin_amdgcn_ds_bpermute(hb, __float_as_int(denp)));
    float rdh = 1.f / den;

    if (!MEAN){
        if (l < 16){                       // g == 0 lanes write features 8m..8m+7
            float4 b0 = *(const float4*)(bias + m * 8);
            float4 b1 = *(const float4*)(bias + m * 8 + 4);
            float e0 = elu_f(acc[0] * rdh + b0.x);
            float e1 = elu_f(acc[1] * rdh + b0.y);
            float e2 = elu_f(acc[2] * rdh + b0.z);
            float e3 = elu_f(acc[3] * rdh + b0.w);
            float e4 = elu_f(acc[4] * rdh + b1.x);
            float e5 = elu_f(acc[5] * rdh + b1.y);
            float e6 = elu_f(acc[6] * rdh + b1.z);
            float e7 = elu_f(acc[7] * rdh + b1.w);
            uint4 ov;
            ov.x = f2h2(e0, e1); ov.y = f2h2(e2, e3);
            ov.z = f2h2(e4, e5); ov.w = f2h2(e6, e7);
            *(uint4*)(O + (size_t)n * 128 + m * 8) = ov;
        }
    } else {
        float v[8];
        #pragma unroll
        for (int q = 0; q < 8; q++) v[q] = acc[q] * rdh;
        #pragma unroll
        for (int q = 0; q < 8; q++){
            v[q] += __shfl_xor(v[q], 4);   // sum heads (lane bits 2,3)
            v[q] += __shfl_xor(v[q], 8);
        }
        float part = 0.f;
        if (l < 4){                        // lane holds out-features 8l..8l+7
            float4 w0 = *(const float4*)(lw + l * 8);
            float4 w1 = *(const float4*)(lw + l * 8 + 4);
            float e0 = elu_f(v[0] * 0.25f + bias[l * 8 + 0]);
            float e1 = elu_f(v[1] * 0.25f + bias[l * 8 + 1]);
            float e2 = elu_f(v[2] * 0.25f + bias[l * 8 + 2]);
            float e3 = elu_f(v[3] * 0.25f + bias[l * 8 + 3]);
            float e4 = elu_f(v[4] * 0.25f + bias[l * 8 + 4]);
            float e5 = elu_f(v[5] * 0.25f + bias[l * 8 + 5]);
            float e6 = elu_f(v[6] * 0.25f + bias[l * 8 + 6]);
            float e7 = elu_f(v[7] * 0.25f + bias[l * 8 + 7]);
            part = e0 * w0.x + e1 * w0.y + e2 * w0.z + e3 * w0.w
                 + e4 * w1.x + e5 * w1.y + e6 * w1.z + e7 * w1.w;
        }
        part += __shfl_xor(part, 1);
        part += __shfl_xor(part, 2);
        if (l == 0){
            int b = batch[n];
            int slot = (int)(blockIdx.x & 63);
            atomicAdd(&pool2[b * 64 + slot], part + lb[0]);
            atomicAdd(&cnt2[b * 64 + slot], 1.f);
        }
    }
}

// ---------------- final: sum slots, divide ----------------

__global__ void k_final(const float* __restrict__ pool2, const float* __restrict__ cnt2,
                        float* __restrict__ out){
    int g = threadIdx.x;
    if (g < 64){
        float ps = 0.f, cs = 0.f;
        for (int s = 0; s < 64; s++){
            ps += pool2[g * 64 + s];
            cs += cnt2[g * 64 + s];
        }
        out[g] = (cs > 0.f) ? ps / cs : 0.f;
    }
}

// ---------------- launch ----------------

extern "C" void kernel_launch(void* const* d_in, const int* in_sizes, int n_in,
                              void* d_out, int out_size, void* d_ws, size_t ws_size,
                              hipStream_t stream){
    const float* x   = (const float*)d_in[0];
    const int*   ei  = (const int*)  d_in[1];
    const int*   bat = (const int*)  d_in[2];
    const float* W1  = (const float*)d_in[3];
    const float* a1s = (const float*)d_in[4];
    const float* a1d = (const float*)d_in[5];
    const float* b1  = (const float*)d_in[6];
    const float* W2  = (const float*)d_in[7];
    const float* a2s = (const float*)d_in[8];
    const float* a2d = (const float*)d_in[9];
    const float* b2  = (const float*)d_in[10];
    const float* W3  = (const float*)d_in[11];
    const float* a3s = (const float*)d_in[12];
    const float* a3d = (const float*)d_in[13];
    const float* b3  = (const float*)d_in[14];
    const float* lw  = (const float*)d_in[15];
    const float* lb  = (const float*)d_in[16];
    (void)n_in; (void)out_size; (void)ws_size;

    const int n_nodes = in_sizes[0] / D1;      // 100000
    const int n_edges = in_sizes[1] / 2;       // 1600000
    const int etot    = n_edges + n_nodes;     // 1700000
    const int nbin    = (n_nodes + BIN_NODES - 1) >> NODE_SHIFT;   // 196

    char* p = (char*)d_ws;
    size_t off = 0;
    auto alloc = [&](size_t bytes) -> char* {
        char* r = p + off;
        off = (off + bytes + 511) & ~(size_t)511;
        return r;
    };
    unsigned short* Hh   = (unsigned short*)alloc((size_t)n_nodes * 128 * 2); // 25.6 MB
    unsigned short* Xh   = (unsigned short*)alloc((size_t)n_nodes * 128 * 2); // 25.6 MB
    float*          asrc = (float*)alloc((size_t)n_nodes * 4 * 4);
    float*          adst = (float*)alloc((size_t)n_nodes * 4 * 4);
    unsigned short* Bp   = (unsigned short*)alloc(3 * 16384 * 2);
    int*      rowptr  = (int*)alloc((size_t)(n_nodes + 1) * 4);
    int*      eidx    = (int*)alloc((size_t)etot * 4);
    unsigned* staged  = (unsigned*)alloc((size_t)etot * 4);        // 6.8 MB packed
    int*      binCnt  = (int*)alloc(MAXBIN * 4);
    int*      binStart= (int*)alloc((MAXBIN + 1) * 4);
    int*      binCur  = (int*)alloc(MAXBIN * 4);
    float*    pool2   = (float*)alloc(64 * 64 * 4);
    float*    cnt2    = (float*)alloc(64 * 64 * 4);

    hipMemsetAsync(binCnt, 0, MAXBIN * 4, stream);
    hipMemsetAsync(pool2, 0, 64 * 64 * 4, stream);
    hipMemsetAsync(cnt2, 0, 64 * 64 * 4, stream);

    k_prepw<<<192, 256, 0, stream>>>(W1, W2, W3, Bp);

    int cb = (etot + 4095) / 4096;             // 416 chunks
    kb_hist<<<cb, 256, 0, stream>>>(ei, binCnt, n_edges, etot, nbin);
    kb_scan<<<1, 64, 0, stream>>>(binCnt, binStart, binCur, nbin, rowptr, n_nodes, etot);
    kb_scatter<<<cb, 256, 0, stream>>>(ei, binCur, staged, n_edges, etot, nbin);
    kb_final<<<nbin, 512, 0, stream>>>(staged, binStart, rowptr, eidx, n_nodes);

    int mb = (n_nodes + 127) / 128;
    int rb = (n_nodes + 3) / 4;

    // layer 1 (fp32 x -> f16 in registers)
    k_mgemm<1><<<mb, 256, 0, stream>>>(x, nullptr, Bp,
                                       a1s, a1d, Hh, asrc, adst, n_nodes);
    k_aggr<0><<<rb, 256, 0, stream>>>((const unsigned*)Hh, asrc, adst, rowptr, eidx,
                                      b1, Xh, nullptr, nullptr, nullptr,
                                      nullptr, nullptr, n_nodes);
    // layer 2
    k_mgemm<0><<<mb, 256, 0, stream>>>(nullptr, Xh, Bp + 16384,
                                       a2s, a2d, Hh, asrc, adst, n_nodes);
    k_aggr<0><<<rb, 256, 0, stream>>>((const unsigned*)Hh, asrc, adst, rowptr, eidx,
                                      b2, Xh, nullptr, nullptr, nullptr,
                                      nullptr, nullptr, n_nodes);
    // layer 3 (fused linear + mean-pool readout)
    k_mgemm<0><<<mb, 256, 0, stream>>>(nullptr, Xh, Bp + 32768,
                                       a3s, a3d, Hh, asrc, adst, n_nodes);
    k_aggr<1><<<rb, 256, 0, stream>>>((const unsigned*)Hh, asrc, adst, rowptr, eidx,
                                      b3, nullptr, bat, lw, lb,
                                      pool2, cnt2, n_nodes);

    k_final<<<1, 64, 0, stream>>>(pool2, cnt2, (float*)d_out);
}

// Round 5
// 495.573 us; speedup vs baseline: 1.0072x; 1.0072x over previous
//
#include <hip/hip_runtime.h>
#include <hip/hip_fp16.h>
#include <math.h>

#define D1 128
#define NEG 0.2f
#define NODE_SHIFT 9
#define BIN_NODES 512
#define MAXBIN 256

typedef _Float16 v8h __attribute__((ext_vector_type(8)));
typedef float v4f __attribute__((ext_vector_type(4)));

__device__ __forceinline__ float elu_f(float v){ return v > 0.f ? v : __expf(v) - 1.f; }

__device__ __forceinline__ unsigned f2h2(float a, float b){           // a->low, b->high
    return ((unsigned)__half_as_ushort(__float2half_rn(b)) << 16) |
           (unsigned)__half_as_ushort(__float2half_rn(a));
}
__device__ __forceinline__ float2 h2f2(unsigned u){
    float lo = __half2float(__ushort_as_half((unsigned short)(u & 0xffffu)));
    float hi = __half2float(__ushort_as_half((unsigned short)(u >> 16)));
    return make_float2(lo, hi);
}

// ---------------- binned CSR build ----------------
// staged entry: (dstLow << 17) | src   (src < 2^17, dstLow < 2^9)

__global__ __launch_bounds__(256) void kb_hist(const int* __restrict__ ei,
                                               int* __restrict__ binCnt,
                                               int n_edges, int etot, int nbin){
    __shared__ int h[MAXBIN];
    for (int i = threadIdx.x; i < nbin; i += 256) h[i] = 0;
    __syncthreads();
    int stride = gridDim.x * 256;
    for (int e = blockIdx.x * 256 + threadIdx.x; e < etot; e += stride){
        int dst = (e < n_edges) ? ei[n_edges + e] : (e - n_edges);
        atomicAdd(&h[dst >> NODE_SHIFT], 1);
    }
    __syncthreads();
    for (int i = threadIdx.x; i < nbin; i += 256)
        if (h[i]) atomicAdd(&binCnt[i], h[i]);
}

__global__ void kb_scan(const int* __restrict__ binCnt, int* __restrict__ binStart,
                        int* __restrict__ binCursor, int nbin,
                        int* __restrict__ rowptr, int n_nodes, int etot){
    if (threadIdx.x == 0){
        int run = 0;
        for (int b = 0; b < nbin; b++){
            binStart[b] = run; binCursor[b] = run; run += binCnt[b];
        }
        binStart[nbin] = run;
        rowptr[n_nodes] = etot;
    }
}

__global__ __launch_bounds__(256) void kb_scatter(const int* __restrict__ ei,
                                                  int* __restrict__ binCursor,
                                                  unsigned* __restrict__ staged,
                                                  int n_edges, int etot, int nbin){
    __shared__ int cnt[MAXBIN];
    __shared__ int base[MAXBIN];
    int e0 = blockIdx.x * 4096;
    for (int i = threadIdx.x; i < nbin; i += 256) cnt[i] = 0;
    __syncthreads();
    #pragma unroll 4
    for (int r = 0; r < 16; r++){
        int e = e0 + r * 256 + threadIdx.x;
        if (e < etot){
            int dst = (e < n_edges) ? ei[n_edges + e] : (e - n_edges);
            atomicAdd(&cnt[dst >> NODE_SHIFT], 1);
        }
    }
    __syncthreads();
    for (int i = threadIdx.x; i < nbin; i += 256){
        base[i] = cnt[i] ? atomicAdd(&binCursor[i], cnt[i]) : 0;
        cnt[i] = 0;
    }
    __syncthreads();
    #pragma unroll 4
    for (int r = 0; r < 16; r++){
        int e = e0 + r * 256 + threadIdx.x;
        if (e < etot){
            int src, dst;
            if (e < n_edges){ src = ei[e]; dst = ei[n_edges + e]; }
            else            { src = dst = e - n_edges; }
            int b = dst >> NODE_SHIFT;
            int p = base[b] + atomicAdd(&cnt[b], 1);
            staged[p] = ((unsigned)(dst & (BIN_NODES - 1)) << 17) | (unsigned)src;
        }
    }
}

__global__ __launch_bounds__(512) void kb_final(const unsigned* __restrict__ staged,
                                                const int* __restrict__ binStart,
                                                int* __restrict__ rowptr,
                                                int* __restrict__ eidx, int n_nodes){
    __shared__ int deg[BIN_NODES];
    __shared__ int cur[BIN_NODES];
    int b = blockIdx.x;
    int nbase = b << NODE_SHIFT;
    int s0 = binStart[b], s1 = binStart[b + 1];
    deg[threadIdx.x] = 0;
    __syncthreads();
    for (int i = s0 + threadIdx.x; i < s1; i += 512)
        atomicAdd(&deg[staged[i] >> 17], 1);
    __syncthreads();
    int v = deg[threadIdx.x];
    cur[threadIdx.x] = v;
    __syncthreads();
    for (int off = 1; off < BIN_NODES; off <<= 1){
        int t = (threadIdx.x >= off) ? cur[threadIdx.x - off] : 0;
        __syncthreads();
        cur[threadIdx.x] += t;
        __syncthreads();
    }
    int excl = cur[threadIdx.x] - v;           // exclusive prefix within bin
    int node = nbase + threadIdx.x;
    if (node < n_nodes) rowptr[node] = s0 + excl;
    cur[threadIdx.x] = s0 + excl;              // becomes cursor
    __syncthreads();
    for (int i = s0 + threadIdx.x; i < s1; i += 512){
        unsigned pr = staged[i];
        int p = atomicAdd(&cur[pr >> 17], 1);
        eidx[p] = (int)(pr & 0x1FFFFu);
    }
}

// ---------------- weight prep: f16 W, k-packed B' layout ----------------
// B[k][j] = W[j][k].  B'[kb][j][kk], kb=k>>3, kk=k&7 (f16 bits in ushort).

__global__ void k_prepw(const float* __restrict__ W1, const float* __restrict__ W2,
                        const float* __restrict__ W3, unsigned short* __restrict__ Bp){
    int t = blockIdx.x * 256 + threadIdx.x;          // 0..49151
    if (t >= 49152) return;
    int w = t >> 14;
    int r = t & 16383;
    int k = r >> 7, j = r & 127;
    const float* W = (w == 0) ? W1 : (w == 1) ? W2 : W3;
    float val = W[j * 128 + k];
    int idx = (k >> 3) * 1024 + j * 8 + (k & 7);
    Bp[w * 16384 + idx] = __half_as_ushort(__float2half_rn(val));
}

// ---------------- f16 MFMA GEMM + fused attention coefficients ----------------
// H = X @ W.T, all operands fp16, fp32 accumulate. A fragments fully hoisted
// (8 x v8h = 32 VGPR), B staged once in 32 KB LDS, one barrier, 64-MFMA stream.
// mfma_f32_16x16x32_f16: A[m=lane&15][k=quad*8+j]; C/D[row=quad*4+reg][col=lane&15].

template<int FP32SRC>
__global__ __launch_bounds__(256, 4) void k_mgemm(
        const float* __restrict__ Xf, const unsigned short* __restrict__ Xh,
        const unsigned short* __restrict__ Bp,
        const float* __restrict__ aw_s, const float* __restrict__ aw_d,
        unsigned short* __restrict__ Hh,
        float* __restrict__ asrc, float* __restrict__ adst, int n_rows){
    __shared__ unsigned short Bs[16384];         // 32 KB: whole B panel, f16
    int lane = threadIdx.x & 63;
    int wv   = threadIdx.x >> 6;
    int li = lane & 15, quad = lane >> 4;
    int r0 = blockIdx.x * 128 + wv * 32;

    int row0 = r0 + li;
    int row1 = r0 + 16 + li;
    int rc0 = row0 < n_rows ? row0 : 0;
    int rc1 = row1 < n_rows ? row1 : 0;

    // hoist all A fragments (independent of LDS staging)
    v8h a0[4], a1[4];
    #pragma unroll
    for (int ks = 0; ks < 4; ks++){
        int koff = ks * 32 + quad * 8;
        if (FP32SRC){
            float f0[8], f1[8];
            *(float4*)&f0[0] = *(const float4*)(Xf + (size_t)rc0 * 128 + koff);
            *(float4*)&f0[4] = *(const float4*)(Xf + (size_t)rc0 * 128 + koff + 4);
            *(float4*)&f1[0] = *(const float4*)(Xf + (size_t)rc1 * 128 + koff);
            *(float4*)&f1[4] = *(const float4*)(Xf + (size_t)rc1 * 128 + koff + 4);
            #pragma unroll
            for (int i = 0; i < 8; i++){
                a0[ks][i] = (_Float16)f0[i];
                a1[ks][i] = (_Float16)f1[i];
            }
        } else {
            a0[ks] = *(const v8h*)(Xh + (size_t)rc0 * 128 + koff);
            a1[ks] = *(const v8h*)(Xh + (size_t)rc1 * 128 + koff);
        }
    }

    // stage whole B panel: 2048 float4, 8 per thread
    #pragma unroll
    for (int i = 0; i < 8; i++){
        int idx = threadIdx.x + i * 256;
        ((float4*)Bs)[idx] = ((const float4*)Bp)[idx];
    }
    __syncthreads();

    v4f acc[2][8];
    #pragma unroll
    for (int m = 0; m < 2; m++)
        #pragma unroll
        for (int t = 0; t < 8; t++)
            acc[m][t] = (v4f){0.f, 0.f, 0.f, 0.f};

    #pragma unroll
    for (int ks = 0; ks < 4; ks++){
        #pragma unroll
        for (int t = 0; t < 8; t++){
            int bo = (ks * 4 + quad) * 1024 + (t * 16 + li) * 8;
            v8h b = *(const v8h*)(Bs + bo);
            acc[0][t] = __builtin_amdgcn_mfma_f32_16x16x32_f16(a0[ks], b, acc[0][t], 0, 0, 0);
            acc[1][t] = __builtin_amdgcn_mfma_f32_16x16x32_f16(a1[ks], b, acc[1][t], 0, 0, 0);
        }
    }

    // epilogue 1: fp16 mirror
    #pragma unroll
    for (int m = 0; m < 2; m++){
        #pragma unroll
        for (int t = 0; t < 8; t++){
            #pragma unroll
            for (int r = 0; r < 4; r++){
                float v  = acc[m][t][r];
                float vo = __shfl_xor(v, 1);
                if (!(li & 1)){
                    int row = r0 + m * 16 + quad * 4 + r;
                    if (row < n_rows)
                        *(unsigned*)(Hh + (size_t)row * 128 + t * 16 + li) = f2h2(v, vo);
                }
            }
        }
    }

    // epilogue 2: fused attention coefficients (fp32)
    float as8[8], ad8[8];
    #pragma unroll
    for (int t = 0; t < 8; t++){
        as8[t] = aw_s[t * 16 + li];
        ad8[t] = aw_d[t * 16 + li];
    }
    #pragma unroll
    for (int m = 0; m < 2; m++){
        #pragma unroll
        for (int r = 0; r < 4; r++){
            float sp[4], dp[4];
            #pragma unroll
            for (int h = 0; h < 4; h++){
                sp[h] = acc[m][2*h][r] * as8[2*h] + acc[m][2*h+1][r] * as8[2*h+1];
                dp[h] = acc[m][2*h][r] * ad8[2*h] + acc[m][2*h+1][r] * ad8[2*h+1];
            }
            #pragma unroll
            for (int off = 1; off < 16; off <<= 1){
                #pragma unroll
                for (int h = 0; h < 4; h++){
                    sp[h] += __shfl_xor(sp[h], off);
                    dp[h] += __shfl_xor(dp[h], off);
                }
            }
            if (li == 0){
                int row = r0 + m * 16 + quad * 4 + r;
                if (row < n_rows){
                    ((float4*)asrc)[row] = make_float4(sp[0], sp[1], sp[2], sp[3]);
                    ((float4*)adst)[row] = make_float4(dp[0], dp[1], dp[2], dp[3]);
                }
            }
        }
    }
}

// ---------------- fused softmax + aggregation, one wave per node ----------------
// x4-gather layout: lane l = 16g+m; slot t covers edges 4t..4t+3 (group g owns
// edge 4t+g); lane-chunk m owns feature pairs 4m..4m+3 (head m>>2). One dwordx4
// load fetches 4 H-rows. Only nt = ceil(rem/4) slots issue (wave-uniform guards).
// sched_barrier(0) between the load group and consume group forces all tiles
// in flight (MLP), paid for by __launch_bounds__(256,6) register headroom.
// MEAN=1 fuses the linear readout + graph mean-pool (slotted atomics).

__device__ __forceinline__ void cons4(uint4 hv, float w, float* acc){
    unsigned u[4] = {hv.x, hv.y, hv.z, hv.w};
    #pragma unroll
    for (int q = 0; q < 4; q++){
        float2 f = h2f2(u[q]);
        acc[2*q]   = fmaf(w, f.x, acc[2*q]);
        acc[2*q+1] = fmaf(w, f.y, acc[2*q+1]);
    }
}

template<int MEAN>
__global__ __launch_bounds__(256, 6) void k_aggr(
        const unsigned* __restrict__ Hh,
        const float* __restrict__ asrc, const float* __restrict__ adst,
        const int* __restrict__ rowptr, const int* __restrict__ eidx,
        const float* __restrict__ bias,
        unsigned short* __restrict__ O,
        const int* __restrict__ batch, const float* __restrict__ lw,
        const float* __restrict__ lb,
        float* __restrict__ pool2, float* __restrict__ cnt2, int n_nodes){
    int lane = threadIdx.x & 63;
    int wid  = threadIdx.x >> 6;
    int n = __builtin_amdgcn_readfirstlane(blockIdx.x * 4 + wid);  // wave-uniform node
    if (n >= n_nodes) return;
    int row0 = rowptr[n];
    int deg  = rowptr[n + 1] - row0;
    const int* ep = eidx + row0;
    int l  = lane;
    int eh = l & 3;                        // weight-phase head
    int ej = l >> 2;                       // weight-phase edge slot (0..15)
    int m  = l & 15;                       // 16B chunk within row
    int wb = l & 60;                       // bpermute base: addr_t = ((t&3)<<6) + wb
    int hb = l & 12;                       // den bpermute addr (head m>>2)
    float4 ad = ((const float4*)adst)[n];
    float adw = eh == 0 ? ad.x : eh == 1 ? ad.y : eh == 2 ? ad.z : ad.w;

    const uint4* H4 = (const uint4*)Hh;
    float acc[8];                          // features 8m..8m+7, edges == g (mod 4)
    #pragma unroll
    for (int q = 0; q < 8; q++) acc[q] = 0.f;
    float denp = 0.f;

    for (int i = 0; i < deg; i += 32){
        int rem = deg - i; if (rem > 32) rem = 32;
        int last = i + rem - 1;

        int j0 = i + ej;
        int sv0 = ep[j0 < last ? j0 : last];
        float t0 = asrc[(size_t)(unsigned)sv0 * 4u + (unsigned)eh] + adw;
        float w0f = __expf(fmaxf(t0, NEG * t0));
        float w0 = (ej < rem) ? w0f : 0.f;
        denp += w0;
        int w0i = __float_as_int(w0);

        int sv1 = sv0;
        int w1i = 0;
        if (rem > 16){
            int j1 = i + 16 + ej;
            sv1 = ep[j1 < last ? j1 : last];
            float t1 = asrc[(size_t)(unsigned)sv1 * 4u + (unsigned)eh] + adw;
            float w1f = __expf(fmaxf(t1, NEG * t1));
            float w1 = (16 + ej < rem) ? w1f : 0.f;
            denp += w1;
            w1i = __float_as_int(w1);
        }

        uint4 hv0, hv1, hv2, hv3, hv4, hv5, hv6, hv7;
#define GLOAD(t, svx) \
        if ((t) * 4 < rem){ \
            int s_ = __builtin_amdgcn_ds_bpermute((((t) & 3) << 6) + wb, svx); \
            hv##t = H4[(unsigned)s_ * 16u + (unsigned)m]; \
        }
#define GCONS(t, wxi) \
        if ((t) * 4 < rem){ \
            float wt_ = __int_as_float(__builtin_amdgcn_ds_bpermute((((t) & 3) << 6) + wb, wxi)); \
            cons4(hv##t, wt_, acc); \
        }
        GLOAD(0, sv0) GLOAD(1, sv0) GLOAD(2, sv0) GLOAD(3, sv0)
        GLOAD(4, sv1) GLOAD(5, sv1) GLOAD(6, sv1) GLOAD(7, sv1)
        __builtin_amdgcn_sched_barrier(0);   // keep all tiles in flight
        GCONS(0, w0i) GCONS(1, w0i) GCONS(2, w0i) GCONS(3, w0i)
        GCONS(4, w1i) GCONS(5, w1i) GCONS(6, w1i) GCONS(7, w1i)
#undef GLOAD
#undef GCONS
    }

    // reduce over edge groups g (lane bits 4,5)
    #pragma unroll
    for (int q = 0; q < 8; q++){
        acc[q] += __shfl_xor(acc[q], 16);
        acc[q] += __shfl_xor(acc[q], 32);
    }
    // denominator: sum over edge slots (bits 2..5), then pick head m>>2
    denp += __shfl_xor(denp, 4);
    denp += __shfl_xor(denp, 8);
    denp += __shfl_xor(denp, 16);
    denp += __shfl_xor(denp, 32);
    float den = __int_as_float(__builtin_amdgcn_ds_bpermute(hb, __float_as_int(denp)));
    float rdh = 1.f / den;

    if (!MEAN){
        if (l < 16){                       // g == 0 lanes write features 8m..8m+7
            float4 b0 = *(const float4*)(bias + m * 8);
            float4 b1 = *(const float4*)(bias + m * 8 + 4);
            float e0 = elu_f(acc[0] * rdh + b0.x);
            float e1 = elu_f(acc[1] * rdh + b0.y);
            float e2 = elu_f(acc[2] * rdh + b0.z);
            float e3 = elu_f(acc[3] * rdh + b0.w);
            float e4 = elu_f(acc[4] * rdh + b1.x);
            float e5 = elu_f(acc[5] * rdh + b1.y);
            float e6 = elu_f(acc[6] * rdh + b1.z);
            float e7 = elu_f(acc[7] * rdh + b1.w);
            uint4 ov;
            ov.x = f2h2(e0, e1); ov.y = f2h2(e2, e3);
            ov.z = f2h2(e4, e5); ov.w = f2h2(e6, e7);
            *(uint4*)(O + (size_t)n * 128 + m * 8) = ov;
        }
    } else {
        float v[8];
        #pragma unroll
        for (int q = 0; q < 8; q++) v[q] = acc[q] * rdh;
        #pragma unroll
        for (int q = 0; q < 8; q++){
            v[q] += __shfl_xor(v[q], 4);   // sum heads (lane bits 2,3)
            v[q] += __shfl_xor(v[q], 8);
        }
        float part = 0.f;
        if (l < 4){                        // lane holds out-features 8l..8l+7
            float4 w0 = *(const float4*)(lw + l * 8);
            float4 w1 = *(const float4*)(lw + l * 8 + 4);
            float e0 = elu_f(v[0] * 0.25f + bias[l * 8 + 0]);
            float e1 = elu_f(v[1] * 0.25f + bias[l * 8 + 1]);
            float e2 = elu_f(v[2] * 0.25f + bias[l * 8 + 2]);
            float e3 = elu_f(v[3] * 0.25f + bias[l * 8 + 3]);
            float e4 = elu_f(v[4] * 0.25f + bias[l * 8 + 4]);
            float e5 = elu_f(v[5] * 0.25f + bias[l * 8 + 5]);
            float e6 = elu_f(v[6] * 0.25f + bias[l * 8 + 6]);
            float e7 = elu_f(v[7] * 0.25f + bias[l * 8 + 7]);
            part = e0 * w0.x + e1 * w0.y + e2 * w0.z + e3 * w0.w
                 + e4 * w1.x + e5 * w1.y + e6 * w1.z + e7 * w1.w;
        }
        part += __shfl_xor(part, 1);
        part += __shfl_xor(part, 2);
        if (l == 0){
            int b = batch[n];
            int slot = (int)(blockIdx.x & 63);
            atomicAdd(&pool2[b * 64 + slot], part + lb[0]);
            atomicAdd(&cnt2[b * 64 + slot], 1.f);
        }
    }
}

// ---------------- final: sum slots, divide ----------------

__global__ void k_final(const float* __restrict__ pool2, const float* __restrict__ cnt2,
                        float* __restrict__ out){
    int g = threadIdx.x;
    if (g < 64){
        float ps = 0.f, cs = 0.f;
        for (int s = 0; s < 64; s++){
            ps += pool2[g * 64 + s];
            cs += cnt2[g * 64 + s];
        }
        out[g] = (cs > 0.f) ? ps / cs : 0.f;
    }
}

// ---------------- launch ----------------

extern "C" void kernel_launch(void* const* d_in, const int* in_sizes, int n_in,
                              void* d_out, int out_size, void* d_ws, size_t ws_size,
                              hipStream_t stream){
    const float* x   = (const float*)d_in[0];
    const int*   ei  = (const int*)  d_in[1];
    const int*   bat = (const int*)  d_in[2];
    const float* W1  = (const float*)d_in[3];
    const float* a1s = (const float*)d_in[4];
    const float* a1d = (const float*)d_in[5];
    const float* b1  = (const float*)d_in[6];
    const float* W2  = (const float*)d_in[7];
    const float* a2s = (const float*)d_in[8];
    const float* a2d = (const float*)d_in[9];
    const float* b2  = (const float*)d_in[10];
    const float* W3  = (const float*)d_in[11];
    const float* a3s = (const float*)d_in[12];
    const float* a3d = (const float*)d_in[13];
    const float* b3  = (const float*)d_in[14];
    const float* lw  = (const float*)d_in[15];
    const float* lb  = (const float*)d_in[16];
    (void)n_in; (void)out_size; (void)ws_size;

    const int n_nodes = in_sizes[0] / D1;      // 100000
    const int n_edges = in_sizes[1] / 2;       // 1600000
    const int etot    = n_edges + n_nodes;     // 1700000
    const int nbin    = (n_nodes + BIN_NODES - 1) >> NODE_SHIFT;   // 196

    char* p = (char*)d_ws;
    size_t off = 0;
    auto alloc = [&](size_t bytes) -> char* {
        char* r = p + off;
        off = (off + bytes + 511) & ~(size_t)511;
        return r;
    };
    unsigned short* Hh   = (unsigned short*)alloc((size_t)n_nodes * 128 * 2); // 25.6 MB
    unsigned short* Xh   = (unsigned short*)alloc((size_t)n_nodes * 128 * 2); // 25.6 MB
    float*          asrc = (float*)alloc((size_t)n_nodes * 4 * 4);
    float*          adst = (float*)alloc((size_t)n_nodes * 4 * 4);
    unsigned short* Bp   = (unsigned short*)alloc(3 * 16384 * 2);
    int*      rowptr  = (int*)alloc((size_t)(n_nodes + 1) * 4);
    int*      eidx    = (int*)alloc((size_t)etot * 4);
    unsigned* staged  = (unsigned*)alloc((size_t)etot * 4);        // 6.8 MB packed
    int*      binCnt  = (int*)alloc(MAXBIN * 4);
    int*      binStart= (int*)alloc((MAXBIN + 1) * 4);
    int*      binCur  = (int*)alloc(MAXBIN * 4);
    float*    pool2   = (float*)alloc(64 * 64 * 4);
    float*    cnt2    = (float*)alloc(64 * 64 * 4);

    hipMemsetAsync(binCnt, 0, MAXBIN * 4, stream);
    hipMemsetAsync(pool2, 0, 64 * 64 * 4, stream);
    hipMemsetAsync(cnt2, 0, 64 * 64 * 4, stream);

    k_prepw<<<192, 256, 0, stream>>>(W1, W2, W3, Bp);

    int cb = (etot + 4095) / 4096;             // 416 chunks
    kb_hist<<<cb, 256, 0, stream>>>(ei, binCnt, n_edges, etot, nbin);
    kb_scan<<<1, 64, 0, stream>>>(binCnt, binStart, binCur, nbin, rowptr, n_nodes, etot);
    kb_scatter<<<cb, 256, 0, stream>>>(ei, binCur, staged, n_edges, etot, nbin);
    kb_final<<<nbin, 512, 0, stream>>>(staged, binStart, rowptr, eidx, n_nodes);

    int mb = (n_nodes + 127) / 128;
    int rb = (n_nodes + 3) / 4;

    // layer 1 (fp32 x -> f16 in registers)
    k_mgemm<1><<<mb, 256, 0, stream>>>(x, nullptr, Bp,
                                       a1s, a1d, Hh, asrc, adst, n_nodes);
    k_aggr<0><<<rb, 256, 0, stream>>>((const unsigned*)Hh, asrc, adst, rowptr, eidx,
                                      b1, Xh, nullptr, nullptr, nullptr,
                                      nullptr, nullptr, n_nodes);
    // layer 2
    k_mgemm<0><<<mb, 256, 0, stream>>>(nullptr, Xh, Bp + 16384,
                                       a2s, a2d, Hh, asrc, adst, n_nodes);
    k_aggr<0><<<rb, 256, 0, stream>>>((const unsigned*)Hh, asrc, adst, rowptr, eidx,
                                      b2, Xh, nullptr, nullptr, nullptr,
                                      nullptr, nullptr, n_nodes);
    // layer 3 (fused linear + mean-pool readout)
    k_mgemm<0><<<mb, 256, 0, stream>>>(nullptr, Xh, Bp + 32768,
                                       a3s, a3d, Hh, asrc, adst, n_nodes);
    k_aggr<1><<<rb, 256, 0, stream>>>((const unsigned*)Hh, asrc, adst, rowptr, eidx,
                                      b3, nullptr, bat, lw, lb,
                                      pool2, cnt2, n_nodes);

    k_final<<<1, 64, 0, stream>>>(pool2, cnt2, (float*)d_out);
}

// Round 6
// 486.193 us; speedup vs baseline: 1.0266x; 1.0193x over previous
//
#include <hip/hip_runtime.h>
#include <hip/hip_fp16.h>
#include <math.h>

#define D1 128
#define NEG 0.2f
#define NODE_SHIFT 9
#define BIN_NODES 512
#define MAXBIN 256

typedef _Float16 v8h __attribute__((ext_vector_type(8)));
typedef float v4f __attribute__((ext_vector_type(4)));

__device__ __forceinline__ float elu_f(float v){ return v > 0.f ? v : __expf(v) - 1.f; }

__device__ __forceinline__ unsigned f2h2(float a, float b){           // a->low, b->high
    return ((unsigned)__half_as_ushort(__float2half_rn(b)) << 16) |
           (unsigned)__half_as_ushort(__float2half_rn(a));
}
__device__ __forceinline__ float2 h2f2(unsigned u){
    float lo = __half2float(__ushort_as_half((unsigned short)(u & 0xffffu)));
    float hi = __half2float(__ushort_as_half((unsigned short)(u >> 16)));
    return make_float2(lo, hi);
}

// ---------------- binned CSR build ----------------
// staged entry: (dstLow << 17) | src   (src < 2^17, dstLow < 2^9)

__global__ __launch_bounds__(256) void kb_hist(const int* __restrict__ ei,
                                               int* __restrict__ binCnt,
                                               int n_edges, int etot, int nbin){
    __shared__ int h[MAXBIN];
    for (int i = threadIdx.x; i < nbin; i += 256) h[i] = 0;
    __syncthreads();
    int stride = gridDim.x * 256;
    for (int e = blockIdx.x * 256 + threadIdx.x; e < etot; e += stride){
        int dst = (e < n_edges) ? ei[n_edges + e] : (e - n_edges);
        atomicAdd(&h[dst >> NODE_SHIFT], 1);
    }
    __syncthreads();
    for (int i = threadIdx.x; i < nbin; i += 256)
        if (h[i]) atomicAdd(&binCnt[i], h[i]);
}

// parallel 256-wide LDS scan (serial 1-thread loop was ~10 us of L2 latency)
__global__ __launch_bounds__(256) void kb_scan(const int* __restrict__ binCnt,
                        int* __restrict__ binStart,
                        int* __restrict__ binCursor, int nbin,
                        int* __restrict__ rowptr, int n_nodes, int etot){
    __shared__ int s[MAXBIN];
    int t = threadIdx.x;
    int v = (t < nbin) ? binCnt[t] : 0;
    s[t] = v;
    __syncthreads();
    #pragma unroll
    for (int off = 1; off < MAXBIN; off <<= 1){
        int x = (t >= off) ? s[t - off] : 0;
        __syncthreads();
        s[t] += x;
        __syncthreads();
    }
    int excl = s[t] - v;
    if (t < nbin){
        binStart[t]  = excl;
        binCursor[t] = excl;
    }
    if (t == 0){
        binStart[nbin]  = s[MAXBIN - 1];
        rowptr[n_nodes] = etot;
    }
}

__global__ __launch_bounds__(256) void kb_scatter(const int* __restrict__ ei,
                                                  int* __restrict__ binCursor,
                                                  unsigned* __restrict__ staged,
                                                  int n_edges, int etot, int nbin){
    __shared__ int cnt[MAXBIN];
    __shared__ int base[MAXBIN];
    int e0 = blockIdx.x * 4096;
    for (int i = threadIdx.x; i < nbin; i += 256) cnt[i] = 0;
    __syncthreads();
    #pragma unroll 4
    for (int r = 0; r < 16; r++){
        int e = e0 + r * 256 + threadIdx.x;
        if (e < etot){
            int dst = (e < n_edges) ? ei[n_edges + e] : (e - n_edges);
            atomicAdd(&cnt[dst >> NODE_SHIFT], 1);
        }
    }
    __syncthreads();
    for (int i = threadIdx.x; i < nbin; i += 256){
        base[i] = cnt[i] ? atomicAdd(&binCursor[i], cnt[i]) : 0;
        cnt[i] = 0;
    }
    __syncthreads();
    #pragma unroll 4
    for (int r = 0; r < 16; r++){
        int e = e0 + r * 256 + threadIdx.x;
        if (e < etot){
            int src, dst;
            if (e < n_edges){ src = ei[e]; dst = ei[n_edges + e]; }
            else            { src = dst = e - n_edges; }
            int b = dst >> NODE_SHIFT;
            int p = base[b] + atomicAdd(&cnt[b], 1);
            staged[p] = ((unsigned)(dst & (BIN_NODES - 1)) << 17) | (unsigned)src;
        }
    }
}

__global__ __launch_bounds__(512) void kb_final(const unsigned* __restrict__ staged,
                                                const int* __restrict__ binStart,
                                                int* __restrict__ rowptr,
                                                int* __restrict__ eidx, int n_nodes){
    __shared__ int deg[BIN_NODES];
    __shared__ int cur[BIN_NODES];
    int b = blockIdx.x;
    int nbase = b << NODE_SHIFT;
    int s0 = binStart[b], s1 = binStart[b + 1];
    deg[threadIdx.x] = 0;
    __syncthreads();
    for (int i = s0 + threadIdx.x; i < s1; i += 512)
        atomicAdd(&deg[staged[i] >> 17], 1);
    __syncthreads();
    int v = deg[threadIdx.x];
    cur[threadIdx.x] = v;
    __syncthreads();
    for (int off = 1; off < BIN_NODES; off <<= 1){
        int t = (threadIdx.x >= off) ? cur[threadIdx.x - off] : 0;
        __syncthreads();
        cur[threadIdx.x] += t;
        __syncthreads();
    }
    int excl = cur[threadIdx.x] - v;           // exclusive prefix within bin
    int node = nbase + threadIdx.x;
    if (node < n_nodes) rowptr[node] = s0 + excl;
    cur[threadIdx.x] = s0 + excl;              // becomes cursor
    __syncthreads();
    for (int i = s0 + threadIdx.x; i < s1; i += 512){
        unsigned pr = staged[i];
        int p = atomicAdd(&cur[pr >> 17], 1);
        eidx[p] = (int)(pr & 0x1FFFFu);
    }
}

// ---------------- weight prep: f16 W, k-packed B' layout ----------------
// B[k][j] = W[j][k].  B'[kb][j][kk], kb=k>>3, kk=k&7 (f16 bits in ushort).

__global__ void k_prepw(const float* __restrict__ W1, const float* __restrict__ W2,
                        const float* __restrict__ W3, unsigned short* __restrict__ Bp){
    int t = blockIdx.x * 256 + threadIdx.x;          // 0..49151
    if (t >= 49152) return;
    int w = t >> 14;
    int r = t & 16383;
    int k = r >> 7, j = r & 127;
    const float* W = (w == 0) ? W1 : (w == 1) ? W2 : W3;
    float val = W[j * 128 + k];
    int idx = (k >> 3) * 1024 + j * 8 + (k & 7);
    Bp[w * 16384 + idx] = __half_as_ushort(__float2half_rn(val));
}

// ---------------- f16 MFMA GEMM + fused attention coefficients ----------------
// H = X @ W.T, all operands fp16, fp32 accumulate. A fragments fully hoisted
// (8 x v8h = 32 VGPR), B staged once in 32 KB LDS, one barrier, 64-MFMA stream.
// mfma_f32_16x16x32_f16: A[m=lane&15][k=quad*8+j]; C/D[row=quad*4+reg][col=lane&15].

template<int FP32SRC>
__global__ __launch_bounds__(256, 4) void k_mgemm(
        const float* __restrict__ Xf, const unsigned short* __restrict__ Xh,
        const unsigned short* __restrict__ Bp,
        const float* __restrict__ aw_s, const float* __restrict__ aw_d,
        unsigned short* __restrict__ Hh,
        float* __restrict__ asrc, float* __restrict__ adst, int n_rows){
    __shared__ unsigned short Bs[16384];         // 32 KB: whole B panel, f16
    int lane = threadIdx.x & 63;
    int wv   = threadIdx.x >> 6;
    int li = lane & 15, quad = lane >> 4;
    int r0 = blockIdx.x * 128 + wv * 32;

    int row0 = r0 + li;
    int row1 = r0 + 16 + li;
    int rc0 = row0 < n_rows ? row0 : 0;
    int rc1 = row1 < n_rows ? row1 : 0;

    // hoist all A fragments (independent of LDS staging)
    v8h a0[4], a1[4];
    #pragma unroll
    for (int ks = 0; ks < 4; ks++){
        int koff = ks * 32 + quad * 8;
        if (FP32SRC){
            float f0[8], f1[8];
            *(float4*)&f0[0] = *(const float4*)(Xf + (size_t)rc0 * 128 + koff);
            *(float4*)&f0[4] = *(const float4*)(Xf + (size_t)rc0 * 128 + koff + 4);
            *(float4*)&f1[0] = *(const float4*)(Xf + (size_t)rc1 * 128 + koff);
            *(float4*)&f1[4] = *(const float4*)(Xf + (size_t)rc1 * 128 + koff + 4);
            #pragma unroll
            for (int i = 0; i < 8; i++){
                a0[ks][i] = (_Float16)f0[i];
                a1[ks][i] = (_Float16)f1[i];
            }
        } else {
            a0[ks] = *(const v8h*)(Xh + (size_t)rc0 * 128 + koff);
            a1[ks] = *(const v8h*)(Xh + (size_t)rc1 * 128 + koff);
        }
    }

    // stage whole B panel: 2048 float4, 8 per thread
    #pragma unroll
    for (int i = 0; i < 8; i++){
        int idx = threadIdx.x + i * 256;
        ((float4*)Bs)[idx] = ((const float4*)Bp)[idx];
    }
    __syncthreads();

    v4f acc[2][8];
    #pragma unroll
    for (int m = 0; m < 2; m++)
        #pragma unroll
        for (int t = 0; t < 8; t++)
            acc[m][t] = (v4f){0.f, 0.f, 0.f, 0.f};

    #pragma unroll
    for (int ks = 0; ks < 4; ks++){
        #pragma unroll
        for (int t = 0; t < 8; t++){
            int bo = (ks * 4 + quad) * 1024 + (t * 16 + li) * 8;
            v8h b = *(const v8h*)(Bs + bo);
            acc[0][t] = __builtin_amdgcn_mfma_f32_16x16x32_f16(a0[ks], b, acc[0][t], 0, 0, 0);
            acc[1][t] = __builtin_amdgcn_mfma_f32_16x16x32_f16(a1[ks], b, acc[1][t], 0, 0, 0);
        }
    }

    // epilogue 1: fp16 mirror
    #pragma unroll
    for (int m = 0; m < 2; m++){
        #pragma unroll
        for (int t = 0; t < 8; t++){
            #pragma unroll
            for (int r = 0; r < 4; r++){
                float v  = acc[m][t][r];
                float vo = __shfl_xor(v, 1);
                if (!(li & 1)){
                    int row = r0 + m * 16 + quad * 4 + r;
                    if (row < n_rows)
                        *(unsigned*)(Hh + (size_t)row * 128 + t * 16 + li) = f2h2(v, vo);
                }
            }
        }
    }

    // epilogue 2: fused attention coefficients (fp32)
    float as8[8], ad8[8];
    #pragma unroll
    for (int t = 0; t < 8; t++){
        as8[t] = aw_s[t * 16 + li];
        ad8[t] = aw_d[t * 16 + li];
    }
    #pragma unroll
    for (int m = 0; m < 2; m++){
        #pragma unroll
        for (int r = 0; r < 4; r++){
            float sp[4], dp[4];
            #pragma unroll
            for (int h = 0; h < 4; h++){
                sp[h] = acc[m][2*h][r] * as8[2*h] + acc[m][2*h+1][r] * as8[2*h+1];
                dp[h] = acc[m][2*h][r] * ad8[2*h] + acc[m][2*h+1][r] * ad8[2*h+1];
            }
            #pragma unroll
            for (int off = 1; off < 16; off <<= 1){
                #pragma unroll
                for (int h = 0; h < 4; h++){
                    sp[h] += __shfl_xor(sp[h], off);
                    dp[h] += __shfl_xor(dp[h], off);
                }
            }
            if (li == 0){
                int row = r0 + m * 16 + quad * 4 + r;
                if (row < n_rows){
                    ((float4*)asrc)[row] = make_float4(sp[0], sp[1], sp[2], sp[3]);
                    ((float4*)adst)[row] = make_float4(dp[0], dp[1], dp[2], dp[3]);
                }
            }
        }
    }
}

// ---------------- fused softmax + aggregation, one wave per node ----------------
// Round-3 structure (fastest measured): x4-gather layout, lane l = 16g+m; slot t
// covers edges 4t..4t+3; lane-chunk m owns feature pairs 4m..4m+3. One dwordx4
// load fetches 4 H-rows. Only ceil(rem/4) slots issue (wave-uniform guards).
// No sched_barrier, no asm: the compiler's own schedule (incl. cross-iteration
// pipelining) measured best. MEAN=1 fuses linear readout + graph mean-pool.

__device__ __forceinline__ void cons4(uint4 hv, float w, float* acc){
    unsigned u[4] = {hv.x, hv.y, hv.z, hv.w};
    #pragma unroll
    for (int q = 0; q < 4; q++){
        float2 f = h2f2(u[q]);
        acc[2*q]   = fmaf(w, f.x, acc[2*q]);
        acc[2*q+1] = fmaf(w, f.y, acc[2*q+1]);
    }
}

template<int MEAN>
__global__ __launch_bounds__(256, 8) void k_aggr(
        const unsigned* __restrict__ Hh,
        const float* __restrict__ asrc, const float* __restrict__ adst,
        const int* __restrict__ rowptr, const int* __restrict__ eidx,
        const float* __restrict__ bias,
        unsigned short* __restrict__ O,
        const int* __restrict__ batch, const float* __restrict__ lw,
        const float* __restrict__ lb,
        float* __restrict__ pool2, float* __restrict__ cnt2, int n_nodes){
    int lane = threadIdx.x & 63;
    int wid  = threadIdx.x >> 6;
    int n = __builtin_amdgcn_readfirstlane(blockIdx.x * 4 + wid);  // wave-uniform node
    if (n >= n_nodes) return;
    int row0 = rowptr[n];
    int deg  = rowptr[n + 1] - row0;
    const int* ep = eidx + row0;
    int l  = lane;
    int eh = l & 3;                        // weight-phase head
    int ej = l >> 2;                       // weight-phase edge slot (0..15)
    int m  = l & 15;                       // 16B chunk within row
    int wb = l & 60;                       // bpermute base: addr_t = ((t&3)<<6) + wb
    int hb = l & 12;                       // den bpermute addr (head m>>2)
    float4 ad = ((const float4*)adst)[n];
    float adw = eh == 0 ? ad.x : eh == 1 ? ad.y : eh == 2 ? ad.z : ad.w;

    const uint4* H4 = (const uint4*)Hh;
    float acc[8];                          // features 8m..8m+7, edges == g (mod 4)
    #pragma unroll
    for (int q = 0; q < 8; q++) acc[q] = 0.f;
    float denp = 0.f;

    for (int i = 0; i < deg; i += 32){
        int rem = deg - i; if (rem > 32) rem = 32;
        int last = i + rem - 1;

        int j0 = i + ej;
        int sv0 = ep[j0 < last ? j0 : last];
        float t0 = asrc[(size_t)(unsigned)sv0 * 4u + (unsigned)eh] + adw;
        float w0f = __expf(fmaxf(t0, NEG * t0));
        float w0 = (ej < rem) ? w0f : 0.f;
        denp += w0;
        int w0i = __float_as_int(w0);

        int sv1 = sv0;
        int w1i = 0;
        if (rem > 16){
            int j1 = i + 16 + ej;
            sv1 = ep[j1 < last ? j1 : last];
            float t1 = asrc[(size_t)(unsigned)sv1 * 4u + (unsigned)eh] + adw;
            float w1f = __expf(fmaxf(t1, NEG * t1));
            float w1 = (16 + ej < rem) ? w1f : 0.f;
            denp += w1;
            w1i = __float_as_int(w1);
        }

        uint4 hv0, hv1, hv2, hv3, hv4, hv5, hv6, hv7;
#define GLOAD(t, svx) \
        if ((t) * 4 < rem){ \
            int s_ = __builtin_amdgcn_ds_bpermute((((t) & 3) << 6) + wb, svx); \
            hv##t = H4[(unsigned)s_ * 16u + (unsigned)m]; \
        }
#define GCONS(t, wxi) \
        if ((t) * 4 < rem){ \
            float wt_ = __int_as_float(__builtin_amdgcn_ds_bpermute((((t) & 3) << 6) + wb, wxi)); \
            cons4(hv##t, wt_, acc); \
        }
        GLOAD(0, sv0) GLOAD(1, sv0) GLOAD(2, sv0) GLOAD(3, sv0)
        GLOAD(4, sv1) GLOAD(5, sv1) GLOAD(6, sv1) GLOAD(7, sv1)
        GCONS(0, w0i) GCONS(1, w0i) GCONS(2, w0i) GCONS(3, w0i)
        GCONS(4, w1i) GCONS(5, w1i) GCONS(6, w1i) GCONS(7, w1i)
#undef GLOAD
#undef GCONS
    }

    // reduce over edge groups g (lane bits 4,5)
    #pragma unroll
    for (int q = 0; q < 8; q++){
        acc[q] += __shfl_xor(acc[q], 16);
        acc[q] += __shfl_xor(acc[q], 32);
    }
    // denominator: sum over edge slots (bits 2..5), then pick head m>>2
    denp += __shfl_xor(denp, 4);
    denp += __shfl_xor(denp, 8);
    denp += __shfl_xor(denp, 16);
    denp += __shfl_xor(denp, 32);
    float den = __int_as_float(__builtin_amdgcn_ds_bpermute(hb, __float_as_int(denp)));
    float rdh = 1.f / den;

    if (!MEAN){
        if (l < 16){                       // g == 0 lanes write features 8m..8m+7
            float4 b0 = *(const float4*)(bias + m * 8);
            float4 b1 = *(const float4*)(bias + m * 8 + 4);
            float e0 = elu_f(acc[0] * rdh + b0.x);
            float e1 = elu_f(acc[1] * rdh + b0.y);
            float e2 = elu_f(acc[2] * rdh + b0.z);
            float e3 = elu_f(acc[3] * rdh + b0.w);
            float e4 = elu_f(acc[4] * rdh + b1.x);
            float e5 = elu_f(acc[5] * rdh + b1.y);
            float e6 = elu_f(acc[6] * rdh + b1.z);
            float e7 = elu_f(acc[7] * rdh + b1.w);
            uint4 ov;
            ov.x = f2h2(e0, e1); ov.y = f2h2(e2, e3);
            ov.z = f2h2(e4, e5); ov.w = f2h2(e6, e7);
            *(uint4*)(O + (size_t)n * 128 + m * 8) = ov;
        }
    } else {
        float v[8];
        #pragma unroll
        for (int q = 0; q < 8; q++) v[q] = acc[q] * rdh;
        #pragma unroll
        for (int q = 0; q < 8; q++){
            v[q] += __shfl_xor(v[q], 4);   // sum heads (lane bits 2,3)
            v[q] += __shfl_xor(v[q], 8);
        }
        float part = 0.f;
        if (l < 4){                        // lane holds out-features 8l..8l+7
            float4 w0 = *(const float4*)(lw + l * 8);
            float4 w1 = *(const float4*)(lw + l * 8 + 4);
            float e0 = elu_f(v[0] * 0.25f + bias[l * 8 + 0]);
            float e1 = elu_f(v[1] * 0.25f + bias[l * 8 + 1]);
            float e2 = elu_f(v[2] * 0.25f + bias[l * 8 + 2]);
            float e3 = elu_f(v[3] * 0.25f + bias[l * 8 + 3]);
            float e4 = elu_f(v[4] * 0.25f + bias[l * 8 + 4]);
            float e5 = elu_f(v[5] * 0.25f + bias[l * 8 + 5]);
            float e6 = elu_f(v[6] * 0.25f + bias[l * 8 + 6]);
            float e7 = elu_f(v[7] * 0.25f + bias[l * 8 + 7]);
            part = e0 * w0.x + e1 * w0.y + e2 * w0.z + e3 * w0.w
                 + e4 * w1.x + e5 * w1.y + e6 * w1.z + e7 * w1.w;
        }
        part += __shfl_xor(part, 1);
        part += __shfl_xor(part, 2);
        if (l == 0){
            int b = batch[n];
            int slot = (int)(blockIdx.x & 63);
            atomicAdd(&pool2[b * 64 + slot], part + lb[0]);
            atomicAdd(&cnt2[b * 64 + slot], 1.f);
        }
    }
}

// ---------------- final: sum slots, divide ----------------

__global__ void k_final(const float* __restrict__ pool2, const float* __restrict__ cnt2,
                        float* __restrict__ out){
    int g = threadIdx.x;
    if (g < 64){
        float ps = 0.f, cs = 0.f;
        for (int s = 0; s < 64; s++){
            ps += pool2[g * 64 + s];
            cs += cnt2[g * 64 + s];
        }
        out[g] = (cs > 0.f) ? ps / cs : 0.f;
    }
}

// ---------------- launch ----------------

extern "C" void kernel_launch(void* const* d_in, const int* in_sizes, int n_in,
                              void* d_out, int out_size, void* d_ws, size_t ws_size,
                              hipStream_t stream){
    const float* x   = (const float*)d_in[0];
    const int*   ei  = (const int*)  d_in[1];
    const int*   bat = (const int*)  d_in[2];
    const float* W1  = (const float*)d_in[3];
    const float* a1s = (const float*)d_in[4];
    const float* a1d = (const float*)d_in[5];
    const float* b1  = (const float*)d_in[6];
    const float* W2  = (const float*)d_in[7];
    const float* a2s = (const float*)d_in[8];
    const float* a2d = (const float*)d_in[9];
    const float* b2  = (const float*)d_in[10];
    const float* W3  = (const float*)d_in[11];
    const float* a3s = (const float*)d_in[12];
    const float* a3d = (const float*)d_in[13];
    const float* b3  = (const float*)d_in[14];
    const float* lw  = (const float*)d_in[15];
    const float* lb  = (const float*)d_in[16];
    (void)n_in; (void)out_size; (void)ws_size;

    const int n_nodes = in_sizes[0] / D1;      // 100000
    const int n_edges = in_sizes[1] / 2;       // 1600000
    const int etot    = n_edges + n_nodes;     // 1700000
    const int nbin    = (n_nodes + BIN_NODES - 1) >> NODE_SHIFT;   // 196

    char* p = (char*)d_ws;
    size_t off = 0;
    auto alloc = [&](size_t bytes) -> char* {
        char* r = p + off;
        off = (off + bytes + 511) & ~(size_t)511;
        return r;
    };
    unsigned short* Hh   = (unsigned short*)alloc((size_t)n_nodes * 128 * 2); // 25.6 MB
    unsigned short* Xh   = (unsigned short*)alloc((size_t)n_nodes * 128 * 2); // 25.6 MB
    float*          asrc = (float*)alloc((size_t)n_nodes * 4 * 4);
    float*          adst = (float*)alloc((size_t)n_nodes * 4 * 4);
    unsigned short* Bp   = (unsigned short*)alloc(3 * 16384 * 2);
    int*      rowptr  = (int*)alloc((size_t)(n_nodes + 1) * 4);
    int*      eidx    = (int*)alloc((size_t)etot * 4);
    unsigned* staged  = (unsigned*)alloc((size_t)etot * 4);        // 6.8 MB packed
    int*      binCnt  = (int*)alloc(MAXBIN * 4);
    int*      binStart= (int*)alloc((MAXBIN + 1) * 4);
    int*      binCur  = (int*)alloc(MAXBIN * 4);
    float*    pool2   = (float*)alloc(64 * 64 * 4);
    float*    cnt2    = (float*)alloc(64 * 64 * 4);

    hipMemsetAsync(binCnt, 0, MAXBIN * 4, stream);
    hipMemsetAsync(pool2, 0, 64 * 64 * 4, stream);
    hipMemsetAsync(cnt2, 0, 64 * 64 * 4, stream);

    k_prepw<<<192, 256, 0, stream>>>(W1, W2, W3, Bp);

    int cb = (etot + 4095) / 4096;             // 416 chunks
    kb_hist<<<cb, 256, 0, stream>>>(ei, binCnt, n_edges, etot, nbin);
    kb_scan<<<1, 256, 0, stream>>>(binCnt, binStart, binCur, nbin, rowptr, n_nodes, etot);
    kb_scatter<<<cb, 256, 0, stream>>>(ei, binCur, staged, n_edges, etot, nbin);
    kb_final<<<nbin, 512, 0, stream>>>(staged, binStart, rowptr, eidx, n_nodes);

    int mb = (n_nodes + 127) / 128;
    int rb = (n_nodes + 3) / 4;

    // layer 1 (fp32 x -> f16 in registers)
    k_mgemm<1><<<mb, 256, 0, stream>>>(x, nullptr, Bp,
                                       a1s, a1d, Hh, asrc, adst, n_nodes);
    k_aggr<0><<<rb, 256, 0, stream>>>((const unsigned*)Hh, asrc, adst, rowptr, eidx,
                                      b1, Xh, nullptr, nullptr, nullptr,
                                      nullptr, nullptr, n_nodes);
    // layer 2
    k_mgemm<0><<<mb, 256, 0, stream>>>(nullptr, Xh, Bp + 16384,
                                       a2s, a2d, Hh, asrc, adst, n_nodes);
    k_aggr<0><<<rb, 256, 0, stream>>>((const unsigned*)Hh, asrc, adst, rowptr, eidx,
                                      b2, Xh, nullptr, nullptr, nullptr,
                                      nullptr, nullptr, n_nodes);
    // layer 3 (fused linear + mean-pool readout)
    k_mgemm<0><<<mb, 256, 0, stream>>>(nullptr, Xh, Bp + 32768,
                                       a3s, a3d, Hh, asrc, adst, n_nodes);
    k_aggr<1><<<rb, 256, 0, stream>>>((const unsigned*)Hh, asrc, adst, rowptr, eidx,
                                      b3, nullptr, bat, lw, lb,
                                      pool2, cnt2, n_nodes);

    k_final<<<1, 64, 0, stream>>>(pool2, cnt2, (float*)d_out);
}

// Round 7
// 466.767 us; speedup vs baseline: 1.0694x; 1.0416x over previous
//
#include <hip/hip_runtime.h>
#include <hip/hip_fp16.h>
#include <math.h>

#define D1 128
#define NEG 0.2f
#define NODE_SHIFT 9
#define BIN_NODES 512
#define MAXBIN 256

typedef _Float16 v8h __attribute__((ext_vector_type(8)));
typedef float v4f __attribute__((ext_vector_type(4)));

__device__ __forceinline__ float elu_f(float v){ return v > 0.f ? v : __expf(v) - 1.f; }

__device__ __forceinline__ unsigned f2h2(float a, float b){           // a->low, b->high
    return ((unsigned)__half_as_ushort(__float2half_rn(b)) << 16) |
           (unsigned)__half_as_ushort(__float2half_rn(a));
}
__device__ __forceinline__ float2 h2f2(unsigned u){
    float lo = __half2float(__ushort_as_half((unsigned short)(u & 0xffffu)));
    float hi = __half2float(__ushort_as_half((unsigned short)(u >> 16)));
    return make_float2(lo, hi);
}

// ---------------- binned CSR build ----------------
// staged entry: (dstLow << 17) | src   (src < 2^17, dstLow < 2^9)

__global__ __launch_bounds__(256) void kb_hist(const int* __restrict__ ei,
                                               int* __restrict__ binCnt,
                                               int n_edges, int etot, int nbin){
    __shared__ int h[MAXBIN];
    for (int i = threadIdx.x; i < nbin; i += 256) h[i] = 0;
    __syncthreads();
    int stride = gridDim.x * 256;
    for (int e = blockIdx.x * 256 + threadIdx.x; e < etot; e += stride){
        int dst = (e < n_edges) ? ei[n_edges + e] : (e - n_edges);
        atomicAdd(&h[dst >> NODE_SHIFT], 1);
    }
    __syncthreads();
    for (int i = threadIdx.x; i < nbin; i += 256)
        if (h[i]) atomicAdd(&binCnt[i], h[i]);
}

// parallel 256-wide LDS scan (serial 1-thread loop was ~10 us of L2 latency)
__global__ __launch_bounds__(256) void kb_scan(const int* __restrict__ binCnt,
                        int* __restrict__ binStart,
                        int* __restrict__ binCursor, int nbin,
                        int* __restrict__ rowptr, int n_nodes, int etot){
    __shared__ int s[MAXBIN];
    int t = threadIdx.x;
    int v = (t < nbin) ? binCnt[t] : 0;
    s[t] = v;
    __syncthreads();
    #pragma unroll
    for (int off = 1; off < MAXBIN; off <<= 1){
        int x = (t >= off) ? s[t - off] : 0;
        __syncthreads();
        s[t] += x;
        __syncthreads();
    }
    int excl = s[t] - v;
    if (t < nbin){
        binStart[t]  = excl;
        binCursor[t] = excl;
    }
    if (t == 0){
        binStart[nbin]  = s[MAXBIN - 1];
        rowptr[n_nodes] = etot;
    }
}

__global__ __launch_bounds__(256) void kb_scatter(const int* __restrict__ ei,
                                                  int* __restrict__ binCursor,
                                                  unsigned* __restrict__ staged,
                                                  int n_edges, int etot, int nbin){
    __shared__ int cnt[MAXBIN];
    __shared__ int base[MAXBIN];
    int e0 = blockIdx.x * 4096;
    for (int i = threadIdx.x; i < nbin; i += 256) cnt[i] = 0;
    __syncthreads();
    #pragma unroll 4
    for (int r = 0; r < 16; r++){
        int e = e0 + r * 256 + threadIdx.x;
        if (e < etot){
            int dst = (e < n_edges) ? ei[n_edges + e] : (e - n_edges);
            atomicAdd(&cnt[dst >> NODE_SHIFT], 1);
        }
    }
    __syncthreads();
    for (int i = threadIdx.x; i < nbin; i += 256){
        base[i] = cnt[i] ? atomicAdd(&binCursor[i], cnt[i]) : 0;
        cnt[i] = 0;
    }
    __syncthreads();
    #pragma unroll 4
    for (int r = 0; r < 16; r++){
        int e = e0 + r * 256 + threadIdx.x;
        if (e < etot){
            int src, dst;
            if (e < n_edges){ src = ei[e]; dst = ei[n_edges + e]; }
            else            { src = dst = e - n_edges; }
            int b = dst >> NODE_SHIFT;
            int p = base[b] + atomicAdd(&cnt[b], 1);
            staged[p] = ((unsigned)(dst & (BIN_NODES - 1)) << 17) | (unsigned)src;
        }
    }
}

__global__ __launch_bounds__(512) void kb_final(const unsigned* __restrict__ staged,
                                                const int* __restrict__ binStart,
                                                int* __restrict__ rowptr,
                                                int* __restrict__ eidx, int n_nodes){
    __shared__ int deg[BIN_NODES];
    __shared__ int cur[BIN_NODES];
    int b = blockIdx.x;
    int nbase = b << NODE_SHIFT;
    int s0 = binStart[b], s1 = binStart[b + 1];
    deg[threadIdx.x] = 0;
    __syncthreads();
    for (int i = s0 + threadIdx.x; i < s1; i += 512)
        atomicAdd(&deg[staged[i] >> 17], 1);
    __syncthreads();
    int v = deg[threadIdx.x];
    cur[threadIdx.x] = v;
    __syncthreads();
    for (int off = 1; off < BIN_NODES; off <<= 1){
        int t = (threadIdx.x >= off) ? cur[threadIdx.x - off] : 0;
        __syncthreads();
        cur[threadIdx.x] += t;
        __syncthreads();
    }
    int excl = cur[threadIdx.x] - v;           // exclusive prefix within bin
    int node = nbase + threadIdx.x;
    if (node < n_nodes) rowptr[node] = s0 + excl;
    cur[threadIdx.x] = s0 + excl;              // becomes cursor
    __syncthreads();
    for (int i = s0 + threadIdx.x; i < s1; i += 512){
        unsigned pr = staged[i];
        int p = atomicAdd(&cur[pr >> 17], 1);
        eidx[p] = (int)(pr & 0x1FFFFu);
    }
}

// ---------------- weight prep: f16 W, k-packed B' layout ----------------
// B[k][j] = W[j][k].  B'[kb][j][kk], kb=k>>3, kk=k&7 (f16 bits in ushort).

__global__ void k_prepw(const float* __restrict__ W1, const float* __restrict__ W2,
                        const float* __restrict__ W3, unsigned short* __restrict__ Bp){
    int t = blockIdx.x * 256 + threadIdx.x;          // 0..49151
    if (t >= 49152) return;
    int w = t >> 14;
    int r = t & 16383;
    int k = r >> 7, j = r & 127;
    const float* W = (w == 0) ? W1 : (w == 1) ? W2 : W3;
    float val = W[j * 128 + k];
    int idx = (k >> 3) * 1024 + j * 8 + (k & 7);
    Bp[w * 16384 + idx] = __half_as_ushort(__float2half_rn(val));
}

// ---------------- f16 MFMA GEMM + fused attention coefficients ----------------
// H = X @ W.T, all operands fp16, fp32 accumulate. A fragments fully hoisted
// (8 x v8h = 32 VGPR), B staged once in 32 KB LDS, one barrier, 64-MFMA stream.
// mfma_f32_16x16x32_f16: A[m=lane&15][k=quad*8+j]; C/D[row=quad*4+reg][col=lane&15].

template<int FP32SRC>
__global__ __launch_bounds__(256, 4) void k_mgemm(
        const float* __restrict__ Xf, const unsigned short* __restrict__ Xh,
        const unsigned short* __restrict__ Bp,
        const float* __restrict__ aw_s, const float* __restrict__ aw_d,
        unsigned short* __restrict__ Hh,
        float* __restrict__ asrc, float* __restrict__ adst, int n_rows){
    __shared__ unsigned short Bs[16384];         // 32 KB: whole B panel, f16
    int lane = threadIdx.x & 63;
    int wv   = threadIdx.x >> 6;
    int li = lane & 15, quad = lane >> 4;
    int r0 = blockIdx.x * 128 + wv * 32;

    int row0 = r0 + li;
    int row1 = r0 + 16 + li;
    int rc0 = row0 < n_rows ? row0 : 0;
    int rc1 = row1 < n_rows ? row1 : 0;

    // hoist all A fragments (independent of LDS staging)
    v8h a0[4], a1[4];
    #pragma unroll
    for (int ks = 0; ks < 4; ks++){
        int koff = ks * 32 + quad * 8;
        if (FP32SRC){
            float f0[8], f1[8];
            *(float4*)&f0[0] = *(const float4*)(Xf + (size_t)rc0 * 128 + koff);
            *(float4*)&f0[4] = *(const float4*)(Xf + (size_t)rc0 * 128 + koff + 4);
            *(float4*)&f1[0] = *(const float4*)(Xf + (size_t)rc1 * 128 + koff);
            *(float4*)&f1[4] = *(const float4*)(Xf + (size_t)rc1 * 128 + koff + 4);
            #pragma unroll
            for (int i = 0; i < 8; i++){
                a0[ks][i] = (_Float16)f0[i];
                a1[ks][i] = (_Float16)f1[i];
            }
        } else {
            a0[ks] = *(const v8h*)(Xh + (size_t)rc0 * 128 + koff);
            a1[ks] = *(const v8h*)(Xh + (size_t)rc1 * 128 + koff);
        }
    }

    // stage whole B panel: 2048 float4, 8 per thread
    #pragma unroll
    for (int i = 0; i < 8; i++){
        int idx = threadIdx.x + i * 256;
        ((float4*)Bs)[idx] = ((const float4*)Bp)[idx];
    }
    __syncthreads();

    v4f acc[2][8];
    #pragma unroll
    for (int m = 0; m < 2; m++)
        #pragma unroll
        for (int t = 0; t < 8; t++)
            acc[m][t] = (v4f){0.f, 0.f, 0.f, 0.f};

    #pragma unroll
    for (int ks = 0; ks < 4; ks++){
        #pragma unroll
        for (int t = 0; t < 8; t++){
            int bo = (ks * 4 + quad) * 1024 + (t * 16 + li) * 8;
            v8h b = *(const v8h*)(Bs + bo);
            acc[0][t] = __builtin_amdgcn_mfma_f32_16x16x32_f16(a0[ks], b, acc[0][t], 0, 0, 0);
            acc[1][t] = __builtin_amdgcn_mfma_f32_16x16x32_f16(a1[ks], b, acc[1][t], 0, 0, 0);
        }
    }

    // epilogue 1: fp16 mirror
    #pragma unroll
    for (int m = 0; m < 2; m++){
        #pragma unroll
        for (int t = 0; t < 8; t++){
            #pragma unroll
            for (int r = 0; r < 4; r++){
                float v  = acc[m][t][r];
                float vo = __shfl_xor(v, 1);
                if (!(li & 1)){
                    int row = r0 + m * 16 + quad * 4 + r;
                    if (row < n_rows)
                        *(unsigned*)(Hh + (size_t)row * 128 + t * 16 + li) = f2h2(v, vo);
                }
            }
        }
    }

    // epilogue 2: fused attention coefficients (fp32)
    float as8[8], ad8[8];
    #pragma unroll
    for (int t = 0; t < 8; t++){
        as8[t] = aw_s[t * 16 + li];
        ad8[t] = aw_d[t * 16 + li];
    }
    #pragma unroll
    for (int m = 0; m < 2; m++){
        #pragma unroll
        for (int r = 0; r < 4; r++){
            float sp[4], dp[4];
            #pragma unroll
            for (int h = 0; h < 4; h++){
                sp[h] = acc[m][2*h][r] * as8[2*h] + acc[m][2*h+1][r] * as8[2*h+1];
                dp[h] = acc[m][2*h][r] * ad8[2*h] + acc[m][2*h+1][r] * ad8[2*h+1];
            }
            #pragma unroll
            for (int off = 1; off < 16; off <<= 1){
                #pragma unroll
                for (int h = 0; h < 4; h++){
                    sp[h] += __shfl_xor(sp[h], off);
                    dp[h] += __shfl_xor(dp[h], off);
                }
            }
            if (li == 0){
                int row = r0 + m * 16 + quad * 4 + r;
                if (row < n_rows){
                    ((float4*)asrc)[row] = make_float4(sp[0], sp[1], sp[2], sp[3]);
                    ((float4*)adst)[row] = make_float4(dp[0], dp[1], dp[2], dp[3]);
                }
            }
        }
    }
}

// ---------------- fused softmax + aggregation, one wave per node ----------------
// Round-3 structure (fastest measured): x4-gather layout, lane l = 16g+m; slot t
// covers edges 4t..4t+3; lane-chunk m owns feature pairs 4m..4m+3. One dwordx4
// load fetches 4 H-rows. Only ceil(rem/4) slots issue (wave-uniform guards).
// MEAN=1: linear readout computed in-register, ONE plain 4B store y[n] per wave.
// NO atomics here -- memory-side atomic completion cost ~33 us/dispatch (R4-R6:
// WRITE_SIZE 6250 KB == 200k atomics x 32B sectors, +33 us wave-retire tails).

__device__ __forceinline__ void cons4(uint4 hv, float w, float* acc){
    unsigned u[4] = {hv.x, hv.y, hv.z, hv.w};
    #pragma unroll
    for (int q = 0; q < 4; q++){
        float2 f = h2f2(u[q]);
        acc[2*q]   = fmaf(w, f.x, acc[2*q]);
        acc[2*q+1] = fmaf(w, f.y, acc[2*q+1]);
    }
}

template<int MEAN>
__global__ __launch_bounds__(256, 8) void k_aggr(
        const unsigned* __restrict__ Hh,
        const float* __restrict__ asrc, const float* __restrict__ adst,
        const int* __restrict__ rowptr, const int* __restrict__ eidx,
        const float* __restrict__ bias,
        unsigned short* __restrict__ O,
        const float* __restrict__ lw, const float* __restrict__ lb,
        float* __restrict__ yout, int n_nodes){
    int lane = threadIdx.x & 63;
    int wid  = threadIdx.x >> 6;
    int n = __builtin_amdgcn_readfirstlane(blockIdx.x * 4 + wid);  // wave-uniform node
    if (n >= n_nodes) return;
    int row0 = rowptr[n];
    int deg  = rowptr[n + 1] - row0;
    const int* ep = eidx + row0;
    int l  = lane;
    int eh = l & 3;                        // weight-phase head
    int ej = l >> 2;                       // weight-phase edge slot (0..15)
    int m  = l & 15;                       // 16B chunk within row
    int wb = l & 60;                       // bpermute base: addr_t = ((t&3)<<6) + wb
    int hb = l & 12;                       // den bpermute addr (head m>>2)
    float4 ad = ((const float4*)adst)[n];
    float adw = eh == 0 ? ad.x : eh == 1 ? ad.y : eh == 2 ? ad.z : ad.w;

    const uint4* H4 = (const uint4*)Hh;
    float acc[8];                          // features 8m..8m+7, edges == g (mod 4)
    #pragma unroll
    for (int q = 0; q < 8; q++) acc[q] = 0.f;
    float denp = 0.f;

    for (int i = 0; i < deg; i += 32){
        int rem = deg - i; if (rem > 32) rem = 32;
        int last = i + rem - 1;

        int j0 = i + ej;
        int sv0 = ep[j0 < last ? j0 : last];
        float t0 = asrc[(size_t)(unsigned)sv0 * 4u + (unsigned)eh] + adw;
        float w0f = __expf(fmaxf(t0, NEG * t0));
        float w0 = (ej < rem) ? w0f : 0.f;
        denp += w0;
        int w0i = __float_as_int(w0);

        int sv1 = sv0;
        int w1i = 0;
        if (rem > 16){
            int j1 = i + 16 + ej;
            sv1 = ep[j1 < last ? j1 : last];
            float t1 = asrc[(size_t)(unsigned)sv1 * 4u + (unsigned)eh] + adw;
            float w1f = __expf(fmaxf(t1, NEG * t1));
            float w1 = (16 + ej < rem) ? w1f : 0.f;
            denp += w1;
            w1i = __float_as_int(w1);
        }

        uint4 hv0, hv1, hv2, hv3, hv4, hv5, hv6, hv7;
#define GLOAD(t, svx) \
        if ((t) * 4 < rem){ \
            int s_ = __builtin_amdgcn_ds_bpermute((((t) & 3) << 6) + wb, svx); \
            hv##t = H4[(unsigned)s_ * 16u + (unsigned)m]; \
        }
#define GCONS(t, wxi) \
        if ((t) * 4 < rem){ \
            float wt_ = __int_as_float(__builtin_amdgcn_ds_bpermute((((t) & 3) << 6) + wb, wxi)); \
            cons4(hv##t, wt_, acc); \
        }
        GLOAD(0, sv0) GLOAD(1, sv0) GLOAD(2, sv0) GLOAD(3, sv0)
        GLOAD(4, sv1) GLOAD(5, sv1) GLOAD(6, sv1) GLOAD(7, sv1)
        GCONS(0, w0i) GCONS(1, w0i) GCONS(2, w0i) GCONS(3, w0i)
        GCONS(4, w1i) GCONS(5, w1i) GCONS(6, w1i) GCONS(7, w1i)
#undef GLOAD
#undef GCONS
    }

    // reduce over edge groups g (lane bits 4,5)
    #pragma unroll
    for (int q = 0; q < 8; q++){
        acc[q] += __shfl_xor(acc[q], 16);
        acc[q] += __shfl_xor(acc[q], 32);
    }
    // denominator: sum over edge slots (bits 2..5), then pick head m>>2
    denp += __shfl_xor(denp, 4);
    denp += __shfl_xor(denp, 8);
    denp += __shfl_xor(denp, 16);
    denp += __shfl_xor(denp, 32);
    float den = __int_as_float(__builtin_amdgcn_ds_bpermute(hb, __float_as_int(denp)));
    float rdh = 1.f / den;

    if (!MEAN){
        if (l < 16){                       // g == 0 lanes write features 8m..8m+7
            float4 b0 = *(const float4*)(bias + m * 8);
            float4 b1 = *(const float4*)(bias + m * 8 + 4);
            float e0 = elu_f(acc[0] * rdh + b0.x);
            float e1 = elu_f(acc[1] * rdh + b0.y);
            float e2 = elu_f(acc[2] * rdh + b0.z);
            float e3 = elu_f(acc[3] * rdh + b0.w);
            float e4 = elu_f(acc[4] * rdh + b1.x);
            float e5 = elu_f(acc[5] * rdh + b1.y);
            float e6 = elu_f(acc[6] * rdh + b1.z);
            float e7 = elu_f(acc[7] * rdh + b1.w);
            uint4 ov;
            ov.x = f2h2(e0, e1); ov.y = f2h2(e2, e3);
            ov.z = f2h2(e4, e5); ov.w = f2h2(e6, e7);
            *(uint4*)(O + (size_t)n * 128 + m * 8) = ov;
        }
    } else {
        float v[8];
        #pragma unroll
        for (int q = 0; q < 8; q++) v[q] = acc[q] * rdh;
        #pragma unroll
        for (int q = 0; q < 8; q++){
            v[q] += __shfl_xor(v[q], 4);   // sum heads (lane bits 2,3)
            v[q] += __shfl_xor(v[q], 8);
        }
        float part = 0.f;
        if (l < 4){                        // lane holds out-features 8l..8l+7
            float4 w0 = *(const float4*)(lw + l * 8);
            float4 w1 = *(const float4*)(lw + l * 8 + 4);
            float e0 = elu_f(v[0] * 0.25f + bias[l * 8 + 0]);
            float e1 = elu_f(v[1] * 0.25f + bias[l * 8 + 1]);
            float e2 = elu_f(v[2] * 0.25f + bias[l * 8 + 2]);
            float e3 = elu_f(v[3] * 0.25f + bias[l * 8 + 3]);
            float e4 = elu_f(v[4] * 0.25f + bias[l * 8 + 4]);
            float e5 = elu_f(v[5] * 0.25f + bias[l * 8 + 5]);
            float e6 = elu_f(v[6] * 0.25f + bias[l * 8 + 6]);
            float e7 = elu_f(v[7] * 0.25f + bias[l * 8 + 7]);
            part = e0 * w0.x + e1 * w0.y + e2 * w0.z + e3 * w0.w
                 + e4 * w1.x + e5 * w1.y + e6 * w1.z + e7 * w1.w;
        }
        part += __shfl_xor(part, 1);
        part += __shfl_xor(part, 2);
        if (l == 0)
            yout[n] = part + lb[0];        // plain store; pooling done separately
    }
}

// ---------------- readout: pool per-node scalar y over graphs ----------------

__global__ __launch_bounds__(256) void k_readout(const float* __restrict__ y,
                          const int* __restrict__ batch,
                          float* __restrict__ pool, float* __restrict__ cnt,
                          int n_nodes){
    __shared__ float pl[64];
    __shared__ float cl[64];
    if (threadIdx.x < 64){ pl[threadIdx.x] = 0.f; cl[threadIdx.x] = 0.f; }
    __syncthreads();
    int n = blockIdx.x * 256 + threadIdx.x;
    if (n < n_nodes){
        int b = batch[n];
        atomicAdd(&pl[b], y[n]);
        atomicAdd(&cl[b], 1.f);
    }
    __syncthreads();
    if (threadIdx.x < 64 && cl[threadIdx.x] != 0.f){
        atomicAdd(&pool[threadIdx.x], pl[threadIdx.x]);
        atomicAdd(&cnt[threadIdx.x], cl[threadIdx.x]);
    }
}

__global__ void k_final(const float* __restrict__ pool, const float* __restrict__ cnt,
                        float* __restrict__ out){
    int g = threadIdx.x;
    if (g < 64) out[g] = (cnt[g] > 0.f) ? pool[g] / cnt[g] : 0.f;
}

// ---------------- launch ----------------

extern "C" void kernel_launch(void* const* d_in, const int* in_sizes, int n_in,
                              void* d_out, int out_size, void* d_ws, size_t ws_size,
                              hipStream_t stream){
    const float* x   = (const float*)d_in[0];
    const int*   ei  = (const int*)  d_in[1];
    const int*   bat = (const int*)  d_in[2];
    const float* W1  = (const float*)d_in[3];
    const float* a1s = (const float*)d_in[4];
    const float* a1d = (const float*)d_in[5];
    const float* b1  = (const float*)d_in[6];
    const float* W2  = (const float*)d_in[7];
    const float* a2s = (const float*)d_in[8];
    const float* a2d = (const float*)d_in[9];
    const float* b2  = (const float*)d_in[10];
    const float* W3  = (const float*)d_in[11];
    const float* a3s = (const float*)d_in[12];
    const float* a3d = (const float*)d_in[13];
    const float* b3  = (const float*)d_in[14];
    const float* lw  = (const float*)d_in[15];
    const float* lb  = (const float*)d_in[16];
    (void)n_in; (void)out_size; (void)ws_size;

    const int n_nodes = in_sizes[0] / D1;      // 100000
    const int n_edges = in_sizes[1] / 2;       // 1600000
    const int etot    = n_edges + n_nodes;     // 1700000
    const int nbin    = (n_nodes + BIN_NODES - 1) >> NODE_SHIFT;   // 196

    char* p = (char*)d_ws;
    size_t off = 0;
    auto alloc = [&](size_t bytes) -> char* {
        char* r = p + off;
        off = (off + bytes + 511) & ~(size_t)511;
        return r;
    };
    unsigned short* Hh   = (unsigned short*)alloc((size_t)n_nodes * 128 * 2); // 25.6 MB
    unsigned short* Xh   = (unsigned short*)alloc((size_t)n_nodes * 128 * 2); // 25.6 MB
    float*          asrc = (float*)alloc((size_t)n_nodes * 4 * 4);
    float*          adst = (float*)alloc((size_t)n_nodes * 4 * 4);
    unsigned short* Bp   = (unsigned short*)alloc(3 * 16384 * 2);
    int*      rowptr  = (int*)alloc((size_t)(n_nodes + 1) * 4);
    int*      eidx    = (int*)alloc((size_t)etot * 4);
    unsigned* staged  = (unsigned*)alloc((size_t)etot * 4);        // 6.8 MB packed
    int*      binCnt  = (int*)alloc(MAXBIN * 4);
    int*      binStart= (int*)alloc((MAXBIN + 1) * 4);
    int*      binCur  = (int*)alloc(MAXBIN * 4);
    float*    yv      = (float*)alloc((size_t)n_nodes * 4);        // per-node scalar
    float*    pool    = (float*)alloc(64 * 4);
    float*    cnt     = (float*)alloc(64 * 4);

    hipMemsetAsync(binCnt, 0, MAXBIN * 4, stream);
    hipMemsetAsync(pool, 0, 64 * 4, stream);
    hipMemsetAsync(cnt, 0, 64 * 4, stream);

    k_prepw<<<192, 256, 0, stream>>>(W1, W2, W3, Bp);

    int cb = (etot + 4095) / 4096;             // 416 chunks
    kb_hist<<<cb, 256, 0, stream>>>(ei, binCnt, n_edges, etot, nbin);
    kb_scan<<<1, 256, 0, stream>>>(binCnt, binStart, binCur, nbin, rowptr, n_nodes, etot);
    kb_scatter<<<cb, 256, 0, stream>>>(ei, binCur, staged, n_edges, etot, nbin);
    kb_final<<<nbin, 512, 0, stream>>>(staged, binStart, rowptr, eidx, n_nodes);

    int mb = (n_nodes + 127) / 128;
    int rb = (n_nodes + 3) / 4;

    // layer 1 (fp32 x -> f16 in registers)
    k_mgemm<1><<<mb, 256, 0, stream>>>(x, nullptr, Bp,
                                       a1s, a1d, Hh, asrc, adst, n_nodes);
    k_aggr<0><<<rb, 256, 0, stream>>>((const unsigned*)Hh, asrc, adst, rowptr, eidx,
                                      b1, Xh, nullptr, nullptr, nullptr, n_nodes);
    // layer 2
    k_mgemm<0><<<mb, 256, 0, stream>>>(nullptr, Xh, Bp + 16384,
                                       a2s, a2d, Hh, asrc, adst, n_nodes);
    k_aggr<0><<<rb, 256, 0, stream>>>((const unsigned*)Hh, asrc, adst, rowptr, eidx,
                                      b2, Xh, nullptr, nullptr, nullptr, n_nodes);
    // layer 3 (linear readout in-register, plain y store)
    k_mgemm<0><<<mb, 256, 0, stream>>>(nullptr, Xh, Bp + 32768,
                                       a3s, a3d, Hh, asrc, adst, n_nodes);
    k_aggr<1><<<rb, 256, 0, stream>>>((const unsigned*)Hh, asrc, adst, rowptr, eidx,
                                      b3, nullptr, lw, lb, yv, n_nodes);

    int ob = (n_nodes + 255) / 256;
    k_readout<<<ob, 256, 0, stream>>>(yv, bat, pool, cnt, n_nodes);
    k_final<<<1, 64, 0, stream>>>(pool, cnt, (float*)d_out);
}